// Round 1
// baseline (2201.655 us; speedup 1.0000x reference)
//
#include <hip/hip_runtime.h>
#include <cstddef>

static constexpr int kN = 4096;   // nodes
static constexpr int kF = 512;    // feature dim (= 2H)
static constexpr int kH = 256;    // output dim
static constexpr float kClamp = 1e-6f;

// ---------------- block reduction (blockDim == 256) ----------------
__device__ __forceinline__ float block_reduce_sum(float v, float* sbuf) {
  const int tid = threadIdx.x;
  sbuf[tid] = v;
  __syncthreads();
#pragma unroll
  for (int s = 128; s > 0; s >>= 1) {
    if (tid < s) sbuf[tid] += sbuf[tid + s];
    __syncthreads();
  }
  const float r = sbuf[0];
  __syncthreads();
  return r;
}

// ---------------- generic tiled f32 GEMM ----------------
// C[m][n] = epi( sum_k OpA[m][k] * B[k][n] )
// TRANSA=false: OpA[m][k] = A[m*lda + k]   (A row-major [M][K])
// TRANSA=true : OpA[m][k] = A[k*lda + m]   (A row-major [K][M])
// epi: v = acc * (rowScale ? rowScale[m] : 1) + (bias ? bias[n] : 0); RELU -> max(v,0)
template <int BM, int BN, int TM, int TN, bool TRANSA, bool RELU>
__global__ __launch_bounds__(256) void gemm_f32(
    const float* __restrict__ A, int lda, const float* __restrict__ B, int ldb,
    float* __restrict__ C, int ldc, int K, const float* __restrict__ rowScale,
    const float* __restrict__ bias) {
  constexpr int BK = 16;
  constexpr int PAD = 4;  // stride BM+4 floats: 16B-aligned rows, breaks pow2 banks
  constexpr int NTH = 256;
  __shared__ __align__(16) float As[BK][BM + PAD];
  __shared__ __align__(16) float Bs[BK][BN + PAD];

  const int tid = threadIdx.x;
  const int m0 = blockIdx.y * BM;
  const int n0 = blockIdx.x * BN;
  constexpr int CT = BN / TN;
  const int tm0 = (tid / CT) * TM;
  const int tn0 = (tid % CT) * TN;

  float acc[TM][TN];
#pragma unroll
  for (int i = 0; i < TM; ++i)
#pragma unroll
    for (int j = 0; j < TN; ++j) acc[i][j] = 0.0f;

  for (int k0 = 0; k0 < K; k0 += BK) {
    if (TRANSA) {
      constexpr int R = (BM * BK / 4) / NTH;
#pragma unroll
      for (int r = 0; r < R; ++r) {
        const int q = tid + r * NTH;
        const int k = q / (BM / 4);
        const int mj = (q % (BM / 4)) * 4;
        const float4 v = *(const float4*)(&A[(size_t)(k0 + k) * lda + (m0 + mj)]);
        *(float4*)(&As[k][mj]) = v;
      }
    } else {
      constexpr int R = (BM * (BK / 4)) / NTH;
#pragma unroll
      for (int r = 0; r < R; ++r) {
        const int q = tid + r * NTH;
        const int m = q / (BK / 4);
        const int kj = (q % (BK / 4)) * 4;
        const float4 v = *(const float4*)(&A[(size_t)(m0 + m) * lda + (k0 + kj)]);
        As[kj + 0][m] = v.x;
        As[kj + 1][m] = v.y;
        As[kj + 2][m] = v.z;
        As[kj + 3][m] = v.w;
      }
    }
    {
      constexpr int R = (BK * BN / 4) / NTH;
#pragma unroll
      for (int r = 0; r < R; ++r) {
        const int q = tid + r * NTH;
        const int k = q / (BN / 4);
        const int nj = (q % (BN / 4)) * 4;
        const float4 v = *(const float4*)(&B[(size_t)(k0 + k) * ldb + (n0 + nj)]);
        *(float4*)(&Bs[k][nj]) = v;
      }
    }
    __syncthreads();
#pragma unroll
    for (int kk = 0; kk < BK; ++kk) {
      float af[TM], bf[TN];
#pragma unroll
      for (int i = 0; i < TM; i += 4) {
        const float4 v = *(const float4*)(&As[kk][tm0 + i]);
        af[i] = v.x; af[i + 1] = v.y; af[i + 2] = v.z; af[i + 3] = v.w;
      }
#pragma unroll
      for (int j = 0; j < TN; j += 4) {
        const float4 v = *(const float4*)(&Bs[kk][tn0 + j]);
        bf[j] = v.x; bf[j + 1] = v.y; bf[j + 2] = v.z; bf[j + 3] = v.w;
      }
#pragma unroll
      for (int i = 0; i < TM; ++i)
#pragma unroll
        for (int j = 0; j < TN; ++j) acc[i][j] = fmaf(af[i], bf[j], acc[i][j]);
    }
    __syncthreads();
  }

#pragma unroll
  for (int i = 0; i < TM; ++i) {
    const int row = m0 + tm0 + i;
    const float rs = rowScale ? rowScale[row] : 1.0f;
#pragma unroll
    for (int j = 0; j < TN; j += 4) {
      float vv[4];
#pragma unroll
      for (int u = 0; u < 4; ++u) {
        float t = acc[i][j + u] * rs;
        if (bias) t += bias[n0 + tn0 + j + u];
        if (RELU) t = fmaxf(t, 0.0f);
        vv[u] = t;
      }
      *(float4*)(&C[(size_t)row * ldc + (n0 + tn0 + j)]) =
          make_float4(vv[0], vv[1], vv[2], vv[3]);
    }
  }
}

// ---------------- row stats: m, cs=sqrt(c), sq, csum ----------------
__global__ __launch_bounds__(256) void row_stats_kernel(
    const float* __restrict__ XM, const float* __restrict__ XS,
    float* __restrict__ Mrow, float* __restrict__ CSrow, float* __restrict__ sq,
    float* __restrict__ csum) {
  __shared__ float sbuf[256];
  const int i = blockIdx.x;
  const int tid = threadIdx.x;
  const size_t base = (size_t)i * kF;
  const float x0 = XM[base + tid];
  const float x1 = XM[base + tid + 256];
  const float nrm = block_reduce_sum(x0 * x0 + x1 * x1, sbuf);
  const float inv = 1.0f / fmaxf(sqrtf(nrm), 1e-12f);
  const float m0 = x0 * inv, m1 = x1 * inv;
  Mrow[base + tid] = m0;
  Mrow[base + tid + 256] = m1;
  const float s2 = block_reduce_sum(m0 * m0 + m1 * m1, sbuf);
  if (tid == 0) sq[i] = s2;

  const float e0 = expf(XS[base + tid]);
  const float e1 = expf(XS[base + tid + 256]);
  const float nrm2 = block_reduce_sum(e0 * e0 + e1 * e1, sbuf);
  const float inv2 = 1.0f / fmaxf(sqrtf(nrm2), 1e-12f);
  const float c0 = e0 * inv2, c1 = e1 * inv2;
  const float sc = block_reduce_sum(c0 + c1, sbuf);
  if (tid == 0) csum[i] = sc;
  CSrow[base + tid] = sqrtf(c0);
  CSrow[base + tid + 256] = sqrtf(c1);
}

// ---------------- fused dual NT-GEMM: ws_raw = exp(-res) ----------------
__global__ __launch_bounds__(256) void ws_dual_gemm(
    const float* __restrict__ Mrow, const float* __restrict__ CSrow,
    const float* __restrict__ sq, const float* __restrict__ csum,
    float* __restrict__ WSR) {
  constexpr int BK = 16, PAD = 4;
  __shared__ __align__(16) float Am[BK][64 + PAD];
  __shared__ __align__(16) float Ac[BK][64 + PAD];
  __shared__ __align__(16) float Bm[BK][64 + PAD];
  __shared__ __align__(16) float Bc[BK][64 + PAD];
  const int tid = threadIdx.x;
  const int i0 = blockIdx.y * 64;
  const int j0 = blockIdx.x * 64;
  const int tm0 = (tid / 16) * 4;
  const int tn0 = (tid % 16) * 4;
  float accM[4][4] = {}, accC[4][4] = {};
  const int lm = tid / 4;
  const int lk = (tid % 4) * 4;
  for (int k0 = 0; k0 < kF; k0 += BK) {
    float4 v;
    v = *(const float4*)(&Mrow[(size_t)(i0 + lm) * kF + k0 + lk]);
    Am[lk + 0][lm] = v.x; Am[lk + 1][lm] = v.y; Am[lk + 2][lm] = v.z; Am[lk + 3][lm] = v.w;
    v = *(const float4*)(&CSrow[(size_t)(i0 + lm) * kF + k0 + lk]);
    Ac[lk + 0][lm] = v.x; Ac[lk + 1][lm] = v.y; Ac[lk + 2][lm] = v.z; Ac[lk + 3][lm] = v.w;
    v = *(const float4*)(&Mrow[(size_t)(j0 + lm) * kF + k0 + lk]);
    Bm[lk + 0][lm] = v.x; Bm[lk + 1][lm] = v.y; Bm[lk + 2][lm] = v.z; Bm[lk + 3][lm] = v.w;
    v = *(const float4*)(&CSrow[(size_t)(j0 + lm) * kF + k0 + lk]);
    Bc[lk + 0][lm] = v.x; Bc[lk + 1][lm] = v.y; Bc[lk + 2][lm] = v.z; Bc[lk + 3][lm] = v.w;
    __syncthreads();
#pragma unroll
    for (int kk = 0; kk < BK; ++kk) {
      const float4 a4 = *(const float4*)(&Am[kk][tm0]);
      const float4 c4 = *(const float4*)(&Ac[kk][tm0]);
      const float4 b4 = *(const float4*)(&Bm[kk][tn0]);
      const float4 d4 = *(const float4*)(&Bc[kk][tn0]);
      const float am[4] = {a4.x, a4.y, a4.z, a4.w};
      const float ac[4] = {c4.x, c4.y, c4.z, c4.w};
      const float bm_[4] = {b4.x, b4.y, b4.z, b4.w};
      const float bc[4] = {d4.x, d4.y, d4.z, d4.w};
#pragma unroll
      for (int i = 0; i < 4; ++i)
#pragma unroll
        for (int j = 0; j < 4; ++j) {
          accM[i][j] = fmaf(am[i], bm_[j], accM[i][j]);
          accC[i][j] = fmaf(ac[i], bc[j], accC[i][j]);
        }
    }
    __syncthreads();
  }
  float sqj[4], csj[4];
#pragma unroll
  for (int tj = 0; tj < 4; ++tj) {
    sqj[tj] = sq[j0 + tn0 + tj];
    csj[tj] = csum[j0 + tn0 + tj];
  }
#pragma unroll
  for (int ti = 0; ti < 4; ++ti) {
    const int i = i0 + tm0 + ti;
    const float sqi = sq[i], csi = csum[i];
    float vv[4];
#pragma unroll
    for (int tj = 0; tj < 4; ++tj) {
      const float d2 = fmaxf(sqi + sqj[tj] - 2.0f * accM[ti][tj], 0.0f);
      const float res = d2 + csi + csj[tj] - 2.0f * accC[ti][tj];
      vv[tj] = expf(-res);
    }
    *(float4*)(&WSR[(size_t)i * kN + (j0 + tn0)]) =
        make_float4(vv[0], vv[1], vv[2], vv[3]);
  }
}

// ---------------- row inverse L2 norm of WSR ----------------
__global__ __launch_bounds__(256) void row_invnorm_kernel(
    const float* __restrict__ WSR, float* __restrict__ invn) {
  __shared__ float sbuf[256];
  const int i = blockIdx.x;
  const int tid = threadIdx.x;
  const float4* rp = (const float4*)(WSR + (size_t)i * kN);
  float s = 0.0f;
#pragma unroll
  for (int q = 0; q < (kN / 4) / 256; ++q) {
    const float4 v = rp[tid + q * 256];
    s += v.x * v.x + v.y * v.y + v.z * v.z + v.w * v.w;
  }
  s = block_reduce_sum(s, sbuf);
  if (tid == 0) invn[i] = 1.0f / fmaxf(sqrtf(s), 1e-12f);
}

// ---------------- elementwise adjacency (in place WSR -> A) ----------------
__global__ __launch_bounds__(256) void adjacency_kernel(
    float* __restrict__ W, const float* __restrict__ invn,
    const float* __restrict__ ne, const float* __restrict__ epsm,
    const float* __restrict__ beta_p, const float* __restrict__ delta_p) {
  const float b = beta_p[0];
  const float d = delta_p[0];
  const size_t q = (size_t)blockIdx.x * 256 + threadIdx.x;  // float4 index
  const int i = (int)(q / (kN / 4));
  const int j = (int)(q % (kN / 4)) * 4;
  const size_t off = (size_t)i * kN + j;
  const float inv = invn[i];
  const float4 w4 = *(const float4*)(&W[off]);
  const float4 n4 = *(const float4*)(&ne[off]);
  const float4 e4 = *(const float4*)(&epsm[off]);
  const float wv[4] = {w4.x, w4.y, w4.z, w4.w};
  const float nv[4] = {n4.x, n4.y, n4.z, n4.w};
  const float ev[4] = {e4.x, e4.y, e4.z, e4.w};
  float ov[4];
#pragma unroll
  for (int u = 0; u < 4; ++u) {
    float t = (1.0f - b) * (wv[u] * inv) + b * nv[u];
    t = fminf(fmaxf(t, kClamp), 1.0f - kClamp);
    float L = logf(t / (1.0f - t));
    const float e = fminf(fmaxf(ev[u], kClamp), 1.0f - kClamp);
    L += logf(e / (1.0f - e));
    const float s = 1.0f / (1.0f + expf(-L));
    float v = (s > d) ? s : 0.0f;
    if (j + u == i) v = (v > 0.0f) ? v : 1.0f;  // self-loop fill where missing
    ov[u] = v;
  }
  *(float4*)(&W[off]) = make_float4(ov[0], ov[1], ov[2], ov[3]);
}

// ---------------- column-sum degree (deterministic two-stage) ----------------
__global__ __launch_bounds__(256) void colsum_partial(
    const float* __restrict__ A, float* __restrict__ degp) {
  const int j = blockIdx.x * 256 + threadIdx.x;
  const int c = blockIdx.y;  // 0..31, each covers 128 rows
  float s = 0.0f;
  const int r0 = c * 128;
  for (int i = r0; i < r0 + 128; ++i) s += A[(size_t)i * kN + j];
  degp[(size_t)c * kN + j] = s;
}

__global__ __launch_bounds__(256) void dis_kernel(
    const float* __restrict__ degp, float* __restrict__ dis) {
  const int j = blockIdx.x * 256 + threadIdx.x;
  float s = 0.0f;
#pragma unroll
  for (int c = 0; c < 32; ++c) s += degp[(size_t)c * kN + j];
  dis[j] = (s > 0.0f) ? (1.0f / sqrtf(s)) : 0.0f;
}

// ---------------- launch ----------------
extern "C" void kernel_launch(void* const* d_in, const int* in_sizes, int n_in,
                              void* d_out, int out_size, void* d_ws,
                              size_t ws_size, hipStream_t stream) {
  const float* x = (const float*)d_in[0];
  const float* ne = (const float*)d_in[1];
  const float* beta = (const float*)d_in[2];
  const float* delta = (const float*)d_in[3];
  const float* epsm = (const float*)d_in[4];
  const float* Wm = (const float*)d_in[5];
  const float* bm = (const float*)d_in[6];
  const float* Ws = (const float*)d_in[7];
  const float* bs = (const float*)d_in[8];
  const float* mW0 = (const float*)d_in[9];
  const float* mb0 = (const float*)d_in[10];
  const float* mW1 = (const float*)d_in[11];
  const float* mb1 = (const float*)d_in[12];
  const float* sW0 = (const float*)d_in[13];
  const float* sb0 = (const float*)d_in[14];
  const float* sW1 = (const float*)d_in[15];
  const float* sb1 = (const float*)d_in[16];
  float* out = (float*)d_out;

  float* w = (float*)d_ws;
  float* XM = w;    w += (size_t)kN * kF;   // x_mean; later reused as h_mean
  float* XS = w;    w += (size_t)kN * kF;   // x_std;  later reused as h_std
  float* Mrow = w;  w += (size_t)kN * kF;   // m; later V0m, then V1m
  float* CSrow = w; w += (size_t)kN * kF;   // cs; later V0s, then V1s
  float* WSR = w;   w += (size_t)kN * kN;   // ws_raw; in-place -> A
  float* sq = w;    w += kN;
  float* csum = w;  w += kN;
  float* invn = w;  w += kN;
  float* dis = w;   w += kN;
  float* degp = w;  w += (size_t)32 * kN;

  const dim3 blk(256);

  // 1) x_mean = x@Wm + bm ; x_std = x@Ws + bs
  gemm_f32<128, 64, 8, 4, false, false><<<dim3(kF / 64, kN / 128), blk, 0, stream>>>(
      x, kF, Wm, kF, XM, kF, kF, nullptr, bm);
  gemm_f32<128, 64, 8, 4, false, false><<<dim3(kF / 64, kN / 128), blk, 0, stream>>>(
      x, kF, Ws, kF, XS, kF, kF, nullptr, bs);

  // 2) per-row stats
  row_stats_kernel<<<kN, blk, 0, stream>>>(XM, XS, Mrow, CSrow, sq, csum);

  // 3) fused dual NT-GEMM -> ws_raw
  ws_dual_gemm<<<dim3(kN / 64, kN / 64), blk, 0, stream>>>(Mrow, CSrow, sq, csum, WSR);

  // 4) row inverse l2 norms of ws_raw
  row_invnorm_kernel<<<kN, blk, 0, stream>>>(WSR, invn);

  // 5) adjacency transform in place
  adjacency_kernel<<<((size_t)kN * kN / 4) / 256, blk, 0, stream>>>(
      WSR, invn, ne, epsm, beta, delta);

  // 6) degree column sums -> dis
  colsum_partial<<<dim3(kN / 256, 32), blk, 0, stream>>>(WSR, degp);
  dis_kernel<<<kN / 256, blk, 0, stream>>>(degp, dis);

  // 7) encoders (An never materialized: dis folded into epilogues)
  float* V0m = Mrow;
  float* V0s = CSrow;
  float* hm = XM;
  float* hs = XS;
  float* V1m = Mrow;
  float* V1s = CSrow;

  // V0 = dis[i] * (X @ W0)
  gemm_f32<128, 64, 8, 4, false, false><<<dim3(kF / 64, kN / 128), blk, 0, stream>>>(
      XM, kF, mW0, kF, V0m, kF, kF, dis, nullptr);
  gemm_f32<128, 64, 8, 4, false, false><<<dim3(kF / 64, kN / 128), blk, 0, stream>>>(
      XS, kF, sW0, kF, V0s, kF, kF, dis, nullptr);

  // h = relu(dis[j] * sum_i A[i][j] * V0[i][:] + b0)
  gemm_f32<128, 64, 8, 4, true, true><<<dim3(kF / 64, kN / 128), blk, 0, stream>>>(
      WSR, kN, V0m, kF, hm, kF, kN, dis, mb0);
  gemm_f32<128, 64, 8, 4, true, true><<<dim3(kF / 64, kN / 128), blk, 0, stream>>>(
      WSR, kN, V0s, kF, hs, kF, kN, dis, sb0);

  // V1 = dis[i] * (h @ W1)
  gemm_f32<64, 64, 4, 4, false, false><<<dim3(kH / 64, kN / 64), blk, 0, stream>>>(
      hm, kF, mW1, kH, V1m, kH, kF, dis, nullptr);
  gemm_f32<64, 64, 4, 4, false, false><<<dim3(kH / 64, kN / 64), blk, 0, stream>>>(
      hs, kF, sW1, kH, V1s, kH, kF, dis, nullptr);

  // z = relu(dis[j] * sum_i A[i][j] * V1[i][:] + b1)  -> d_out
  gemm_f32<64, 64, 4, 4, true, true><<<dim3(kH / 64, kN / 64), blk, 0, stream>>>(
      WSR, kN, V1m, kH, out, kH, kN, dis, mb1);
  gemm_f32<64, 64, 4, 4, true, true><<<dim3(kH / 64, kN / 64), blk, 0, stream>>>(
      WSR, kN, V1s, kH, out + (size_t)kN * kH, kH, kN, dis, sb1);
}

// Round 3
// 1502.426 us; speedup vs baseline: 1.4654x; 1.4654x over previous
//
#include <hip/hip_runtime.h>
#include <cstddef>

static constexpr int kN = 4096;
static constexpr int kF = 512;
static constexpr int kH = 256;
static constexpr float kClamp = 1e-6f;

using bf16x8 = __attribute__((ext_vector_type(8))) __bf16;
using f32x4 = __attribute__((ext_vector_type(4))) float;
using ushort8 = __attribute__((ext_vector_type(8))) unsigned short;
using ushort4v = __attribute__((ext_vector_type(4))) unsigned short;

__device__ __forceinline__ unsigned short f2bf(float x) {
  unsigned int u = __float_as_uint(x);
  u += 0x7fffu + ((u >> 16) & 1u);
  return (unsigned short)(u >> 16);
}
__device__ __forceinline__ float bf2f(unsigned short h) {
  return __uint_as_float(((unsigned int)h) << 16);
}
// 3-term bf16 split: x ~= hi + mid + lo (each RTN-even)
__device__ __forceinline__ void split3(float x, unsigned short& h,
                                       unsigned short& m, unsigned short& l) {
  h = f2bf(x);
  const float r1 = x - bf2f(h);
  m = f2bf(r1);
  l = f2bf(r1 - bf2f(m));
}
// split a float4 into three ushort4 vectors (hi/mid/lo)
__device__ __forceinline__ void split3x4(const float4 v, ushort4v& h4,
                                         ushort4v& m4, ushort4v& l4) {
  unsigned short h, m, l;
  split3(v.x, h, m, l); h4.x = h; m4.x = m; l4.x = l;
  split3(v.y, h, m, l); h4.y = h; m4.y = m; l4.y = l;
  split3(v.z, h, m, l); h4.z = h; m4.z = m; l4.z = l;
  split3(v.w, h, m, l); h4.w = h; m4.w = m; l4.w = l;
}

__device__ __forceinline__ bf16x8 ldfrag(const unsigned short* p) {
  ushort8 r = *(const ushort8*)p;
  return __builtin_bit_cast(bf16x8, r);
}
__device__ __forceinline__ f32x4 mfma16(bf16x8 a, bf16x8 b, f32x4 c) {
  return __builtin_amdgcn_mfma_f32_16x16x32_bf16(a, b, c, 0, 0, 0);
}
// 6-product accumulation: hh + hm + mh + mm + hl + lh (rel err ~2^-26)
__device__ __forceinline__ f32x4 mfma_split6(const bf16x8* a3, const bf16x8* b3,
                                             f32x4 acc) {
  acc = mfma16(a3[2], b3[0], acc);
  acc = mfma16(a3[0], b3[2], acc);
  acc = mfma16(a3[1], b3[1], acc);
  acc = mfma16(a3[1], b3[0], acc);
  acc = mfma16(a3[0], b3[1], acc);
  acc = mfma16(a3[0], b3[0], acc);
  return acc;
}

__device__ __forceinline__ void tri_map(int b, int& bi, int& bj) {
  int x = (int)((sqrtf(8.0f * (float)b + 1.0f) - 1.0f) * 0.5f);
  while ((x + 1) * (x + 2) / 2 <= b) ++x;
  while (x * (x + 1) / 2 > b) --x;
  bi = x;
  bj = b - x * (x + 1) / 2;
}

__device__ __forceinline__ float block_reduce_sum(float v, float* sbuf) {
  const int tid = threadIdx.x;
  sbuf[tid] = v;
  __syncthreads();
#pragma unroll
  for (int s = 128; s > 0; s >>= 1) {
    if (tid < s) sbuf[tid] += sbuf[tid + s];
    __syncthreads();
  }
  const float r = sbuf[0];
  __syncthreads();
  return r;
}

// ---------------- generic split-bf16 MFMA GEMM ----------------
// C[m][n] = epi( sum_k A[m][k] * B[n][k] )
// A: [M][K] f32 row-major. B: [N][K] f32 row-major.
// CT=false: C[m][n] at C[m*N+n];  CT=true: C[n*M+m] (transposed out, float4).
template <bool CT, bool RELU>
__global__ __launch_bounds__(256) void mfma_gemm(
    const float* __restrict__ A, const float* __restrict__ B,
    float* __restrict__ C, int M, int N, int K,
    const float* __restrict__ rowScale, const float* __restrict__ bias) {
  constexpr int BM = 128, BN = 64, LDT = 40;
  __shared__ __align__(16) unsigned short Asl[3][BM][LDT];
  __shared__ __align__(16) unsigned short Bsl[3][BN][LDT];
  const int tid = threadIdx.x;
  const int lane = tid & 63;
  const int wave = tid >> 6;
  const int wm = wave >> 1;  // 0..1 -> 64-row slab
  const int wn = wave & 1;   // 0..1 -> 32-col slab
  const int m0 = blockIdx.y * BM;
  const int n0 = blockIdx.x * BN;
  const int sRow = tid >> 3;        // 0..31
  const int sKj = (tid & 7) * 4;    // 0..28
  const int rl = lane & 15;
  const int kq = (lane >> 4) * 8;

  f32x4 acc[4][2];
#pragma unroll
  for (int i = 0; i < 4; ++i)
#pragma unroll
    for (int j = 0; j < 2; ++j) acc[i][j] = (f32x4){0.f, 0.f, 0.f, 0.f};

  for (int k0 = 0; k0 < K; k0 += 32) {
#pragma unroll
    for (int r = 0; r < BM / 32; ++r) {
      const int row = r * 32 + sRow;
      const float4 v = *(const float4*)(&A[(size_t)(m0 + row) * K + k0 + sKj]);
      ushort4v h4, m4, l4;
      split3x4(v, h4, m4, l4);
      *(ushort4v*)(&Asl[0][row][sKj]) = h4;
      *(ushort4v*)(&Asl[1][row][sKj]) = m4;
      *(ushort4v*)(&Asl[2][row][sKj]) = l4;
    }
#pragma unroll
    for (int r = 0; r < BN / 32; ++r) {
      const int row = r * 32 + sRow;
      const float4 v = *(const float4*)(&B[(size_t)(n0 + row) * K + k0 + sKj]);
      ushort4v h4, m4, l4;
      split3x4(v, h4, m4, l4);
      *(ushort4v*)(&Bsl[0][row][sKj]) = h4;
      *(ushort4v*)(&Bsl[1][row][sKj]) = m4;
      *(ushort4v*)(&Bsl[2][row][sKj]) = l4;
    }
    __syncthreads();

    bf16x8 af[4][3], bfr[2][3];
#pragma unroll
    for (int mt = 0; mt < 4; ++mt)
#pragma unroll
      for (int t = 0; t < 3; ++t)
        af[mt][t] = ldfrag(&Asl[t][wm * 64 + mt * 16 + rl][kq]);
#pragma unroll
    for (int nt = 0; nt < 2; ++nt)
#pragma unroll
      for (int t = 0; t < 3; ++t)
        bfr[nt][t] = ldfrag(&Bsl[t][wn * 32 + nt * 16 + rl][kq]);

#pragma unroll
    for (int mt = 0; mt < 4; ++mt)
#pragma unroll
      for (int nt = 0; nt < 2; ++nt)
        acc[mt][nt] = mfma_split6(af[mt], bfr[nt], acc[mt][nt]);
    __syncthreads();
  }

  // epilogue. C/D layout: col = lane&15, row = (lane>>4)*4 + r  [verified m89/m91]
  const int q = lane >> 4;
#pragma unroll
  for (int mt = 0; mt < 4; ++mt) {
#pragma unroll
    for (int nt = 0; nt < 2; ++nt) {
      const int col = n0 + wn * 32 + nt * 16 + rl;
      const int row0 = m0 + wm * 64 + mt * 16 + q * 4;
      if (CT) {
        float4 w;
        float* wp = &w.x;
#pragma unroll
        for (int r = 0; r < 4; ++r) {
          float v = acc[mt][nt][r];
          if (rowScale) v *= rowScale[row0 + r];
          if (RELU) v = fmaxf(v, 0.f);
          wp[r] = v;
        }
        *(float4*)(&C[(size_t)col * M + row0]) = w;
      } else {
        const float bv = bias ? bias[col] : 0.f;
#pragma unroll
        for (int r = 0; r < 4; ++r) {
          float v = acc[mt][nt][r];
          if (rowScale) v *= rowScale[row0 + r];
          v += bv;
          if (RELU) v = fmaxf(v, 0.f);
          C[(size_t)(row0 + r) * N + col] = v;
        }
      }
    }
  }
}

// ---------------- symmetric dual NT-GEMM ws_raw = exp(-res) ----------------
__global__ __launch_bounds__(256) void ws_mfma(
    const float* __restrict__ Mr, const float* __restrict__ CSr,
    const float* __restrict__ sq, const float* __restrict__ csum,
    float* __restrict__ WSR) {
  constexpr int LDT = 40;
  __shared__ __align__(16) unsigned short Am3[3][64][LDT];
  __shared__ __align__(16) unsigned short Ac3[3][64][LDT];
  __shared__ __align__(16) unsigned short Bm3[3][64][LDT];
  __shared__ __align__(16) unsigned short Bc3[3][64][LDT];
  int bi, bj;
  tri_map(blockIdx.x, bi, bj);  // bi >= bj (lower triangle incl diag)
  const int i0 = bi * 64, j0 = bj * 64;
  const int tid = threadIdx.x;
  const int lane = tid & 63;
  const int wave = tid >> 6;
  const int wm = wave >> 1, wn = wave & 1;
  const int sRow = tid >> 3;
  const int sKj = (tid & 7) * 4;
  const int rl = lane & 15;
  const int kq = (lane >> 4) * 8;

  f32x4 aM[2][2], aC[2][2];
#pragma unroll
  for (int i = 0; i < 2; ++i)
#pragma unroll
    for (int j = 0; j < 2; ++j) {
      aM[i][j] = (f32x4){0.f, 0.f, 0.f, 0.f};
      aC[i][j] = (f32x4){0.f, 0.f, 0.f, 0.f};
    }

  for (int k0 = 0; k0 < kF; k0 += 32) {
#pragma unroll
    for (int r = 0; r < 2; ++r) {
      const int row = r * 32 + sRow;
      ushort4v h4, m4, l4;
      float4 v;
      v = *(const float4*)(&Mr[(size_t)(i0 + row) * kF + k0 + sKj]);
      split3x4(v, h4, m4, l4);
      *(ushort4v*)(&Am3[0][row][sKj]) = h4;
      *(ushort4v*)(&Am3[1][row][sKj]) = m4;
      *(ushort4v*)(&Am3[2][row][sKj]) = l4;
      v = *(const float4*)(&CSr[(size_t)(i0 + row) * kF + k0 + sKj]);
      split3x4(v, h4, m4, l4);
      *(ushort4v*)(&Ac3[0][row][sKj]) = h4;
      *(ushort4v*)(&Ac3[1][row][sKj]) = m4;
      *(ushort4v*)(&Ac3[2][row][sKj]) = l4;
      v = *(const float4*)(&Mr[(size_t)(j0 + row) * kF + k0 + sKj]);
      split3x4(v, h4, m4, l4);
      *(ushort4v*)(&Bm3[0][row][sKj]) = h4;
      *(ushort4v*)(&Bm3[1][row][sKj]) = m4;
      *(ushort4v*)(&Bm3[2][row][sKj]) = l4;
      v = *(const float4*)(&CSr[(size_t)(j0 + row) * kF + k0 + sKj]);
      split3x4(v, h4, m4, l4);
      *(ushort4v*)(&Bc3[0][row][sKj]) = h4;
      *(ushort4v*)(&Bc3[1][row][sKj]) = m4;
      *(ushort4v*)(&Bc3[2][row][sKj]) = l4;
    }
    __syncthreads();

    bf16x8 am[2][3], ac[2][3], bm[2][3], bc[2][3];
#pragma unroll
    for (int mt = 0; mt < 2; ++mt)
#pragma unroll
      for (int t = 0; t < 3; ++t) {
        am[mt][t] = ldfrag(&Am3[t][wm * 32 + mt * 16 + rl][kq]);
        ac[mt][t] = ldfrag(&Ac3[t][wm * 32 + mt * 16 + rl][kq]);
      }
#pragma unroll
    for (int nt = 0; nt < 2; ++nt)
#pragma unroll
      for (int t = 0; t < 3; ++t) {
        bm[nt][t] = ldfrag(&Bm3[t][wn * 32 + nt * 16 + rl][kq]);
        bc[nt][t] = ldfrag(&Bc3[t][wn * 32 + nt * 16 + rl][kq]);
      }
#pragma unroll
    for (int mt = 0; mt < 2; ++mt)
#pragma unroll
      for (int nt = 0; nt < 2; ++nt) {
        aM[mt][nt] = mfma_split6(am[mt], bm[nt], aM[mt][nt]);
        aC[mt][nt] = mfma_split6(ac[mt], bc[nt], aC[mt][nt]);
      }
    __syncthreads();
  }

  const int q = lane >> 4;
#pragma unroll
  for (int mt = 0; mt < 2; ++mt) {
#pragma unroll
    for (int nt = 0; nt < 2; ++nt) {
      const int j = j0 + wn * 32 + nt * 16 + rl;
      const int ib = i0 + wm * 32 + mt * 16 + q * 4;
      const float sqj = sq[j], csj = csum[j];
      float4 vv;
      float* vp = &vv.x;
#pragma unroll
      for (int r = 0; r < 4; ++r) {
        const int i = ib + r;
        const float d2 = fmaxf(sq[i] + sqj - 2.0f * aM[mt][nt][r], 0.0f);
        const float res = d2 + csum[i] + csj - 2.0f * aC[mt][nt][r];
        const float v = expf(-res);
        vp[r] = v;
        WSR[(size_t)i * kN + j] = v;
      }
      if (bi != bj) *(float4*)(&WSR[(size_t)j * kN + ib]) = vv;  // symmetry
    }
  }
}

// ---------------- row stats ----------------
__global__ __launch_bounds__(256) void row_stats_kernel(
    const float* __restrict__ XM, const float* __restrict__ XS,
    float* __restrict__ Mrow, float* __restrict__ CSrow, float* __restrict__ sq,
    float* __restrict__ csum) {
  __shared__ float sbuf[256];
  const int i = blockIdx.x;
  const int tid = threadIdx.x;
  const size_t base = (size_t)i * kF;
  const float x0 = XM[base + tid];
  const float x1 = XM[base + tid + 256];
  const float nrm = block_reduce_sum(x0 * x0 + x1 * x1, sbuf);
  const float inv = 1.0f / fmaxf(sqrtf(nrm), 1e-12f);
  const float m0 = x0 * inv, m1 = x1 * inv;
  Mrow[base + tid] = m0;
  Mrow[base + tid + 256] = m1;
  const float s2 = block_reduce_sum(m0 * m0 + m1 * m1, sbuf);
  if (tid == 0) sq[i] = s2;
  const float e0 = expf(XS[base + tid]);
  const float e1 = expf(XS[base + tid + 256]);
  const float nrm2 = block_reduce_sum(e0 * e0 + e1 * e1, sbuf);
  const float inv2 = 1.0f / fmaxf(sqrtf(nrm2), 1e-12f);
  const float c0 = e0 * inv2, c1 = e1 * inv2;
  const float sc = block_reduce_sum(c0 + c1, sbuf);
  if (tid == 0) csum[i] = sc;
  CSrow[base + tid] = sqrtf(c0);
  CSrow[base + tid + 256] = sqrtf(c1);
}

// ---------------- row inverse L2 norm of WSR ----------------
__global__ __launch_bounds__(256) void row_invnorm_kernel(
    const float* __restrict__ WSR, float* __restrict__ invn) {
  __shared__ float sbuf[256];
  const int i = blockIdx.x;
  const int tid = threadIdx.x;
  const float4* rp = (const float4*)(WSR + (size_t)i * kN);
  float s = 0.0f;
#pragma unroll
  for (int q = 0; q < (kN / 4) / 256; ++q) {
    const float4 v = rp[tid + q * 256];
    s += v.x * v.x + v.y * v.y + v.z * v.z + v.w * v.w;
  }
  s = block_reduce_sum(s, sbuf);
  if (tid == 0) invn[i] = 1.0f / fmaxf(sqrtf(s), 1e-12f);
}

// ---------------- adjacency + in-place paired-tile transpose ----------------
__device__ __forceinline__ float adj_val(float w, float inv, float nev, float ev,
                                         float b, float d, bool diag) {
  float t = (1.0f - b) * (w * inv) + b * nev;
  t = fminf(fmaxf(t, kClamp), 1.0f - kClamp);
  float L = logf(t / (1.0f - t));
  const float e = fminf(fmaxf(ev, kClamp), 1.0f - kClamp);
  L += logf(e / (1.0f - e));
  const float s = 1.0f / (1.0f + expf(-L));
  float v = (s > d) ? s : 0.0f;
  if (diag) v = (v > 0.0f) ? v : 1.0f;
  return v;
}

// After this kernel, W holds AdjT: W[j][i] = A(i,j).
__global__ __launch_bounds__(256) void adj_transpose(
    float* __restrict__ W, const float* __restrict__ invn,
    const float* __restrict__ ne, const float* __restrict__ epsm,
    const float* __restrict__ beta_p, const float* __restrict__ delta_p) {
  __shared__ float T0[64][65];
  __shared__ float T1[64][65];
  const float b = beta_p[0];
  const float d = delta_p[0];
  int bi, bj;
  tri_map(blockIdx.x, bi, bj);
  const int i0 = bi * 64, j0 = bj * 64;
  const int tid = threadIdx.x;
  const int rlq = tid >> 4;        // 0..15
  const int cq = (tid & 15) * 4;   // 0..60
#pragma unroll
  for (int p = 0; p < 4; ++p) {
    const int ii = p * 16 + rlq;
    {
      const size_t off = (size_t)(i0 + ii) * kN + j0 + cq;
      const float4 w4 = *(const float4*)(&W[off]);
      const float4 n4 = *(const float4*)(&ne[off]);
      const float4 e4 = *(const float4*)(&epsm[off]);
      const float inv = invn[i0 + ii];
      const float wv[4] = {w4.x, w4.y, w4.z, w4.w};
      const float nv[4] = {n4.x, n4.y, n4.z, n4.w};
      const float ev[4] = {e4.x, e4.y, e4.z, e4.w};
#pragma unroll
      for (int u = 0; u < 4; ++u)
        T0[ii][cq + u] =
            adj_val(wv[u], inv, nv[u], ev[u], b, d, (i0 + ii) == (j0 + cq + u));
    }
    if (bi != bj) {
      const size_t off = (size_t)(j0 + ii) * kN + i0 + cq;
      const float4 w4 = *(const float4*)(&W[off]);
      const float4 n4 = *(const float4*)(&ne[off]);
      const float4 e4 = *(const float4*)(&epsm[off]);
      const float inv = invn[j0 + ii];
      const float wv[4] = {w4.x, w4.y, w4.z, w4.w};
      const float nv[4] = {n4.x, n4.y, n4.z, n4.w};
      const float ev[4] = {e4.x, e4.y, e4.z, e4.w};
#pragma unroll
      for (int u = 0; u < 4; ++u)
        T1[ii][cq + u] = adj_val(wv[u], inv, nv[u], ev[u], b, d, false);
    }
  }
  __syncthreads();
#pragma unroll
  for (int p = 0; p < 4; ++p) {
    const int jj = p * 16 + rlq;
    {
      float4 w = make_float4(T0[cq + 0][jj], T0[cq + 1][jj], T0[cq + 2][jj],
                             T0[cq + 3][jj]);
      *(float4*)(&W[(size_t)(j0 + jj) * kN + i0 + cq]) = w;
    }
    if (bi != bj) {
      float4 w = make_float4(T1[cq + 0][jj], T1[cq + 1][jj], T1[cq + 2][jj],
                             T1[cq + 3][jj]);
      *(float4*)(&W[(size_t)(i0 + jj) * kN + j0 + cq]) = w;
    }
  }
}

// ---------------- deg (row sums of AdjT) -> dis ----------------
__global__ __launch_bounds__(256) void deg_dis_kernel(
    const float* __restrict__ AdjT, float* __restrict__ dis) {
  __shared__ float sbuf[256];
  const int j = blockIdx.x;
  const int tid = threadIdx.x;
  const float4* rp = (const float4*)(AdjT + (size_t)j * kN);
  float s = 0.0f;
#pragma unroll
  for (int q = 0; q < (kN / 4) / 256; ++q) {
    const float4 v = rp[tid + q * 256];
    s += v.x + v.y + v.z + v.w;
  }
  s = block_reduce_sum(s, sbuf);
  if (tid == 0) dis[j] = (s > 0.0f) ? (1.0f / sqrtf(s)) : 0.0f;
}

// ---------------- small f32 transpose: in [R][C] -> out [C][R] ----------------
__global__ __launch_bounds__(256) void transpose_f32(
    const float* __restrict__ in, float* __restrict__ out, int R, int C) {
  const int t = blockIdx.x * 256 + threadIdx.x;
  const int k = t % R;
  const int n = t / R;
  out[(size_t)n * R + k] = in[(size_t)k * C + n];
}

// ---------------- launch ----------------
extern "C" void kernel_launch(void* const* d_in, const int* in_sizes, int n_in,
                              void* d_out, int out_size, void* d_ws,
                              size_t ws_size, hipStream_t stream) {
  const float* x = (const float*)d_in[0];
  const float* ne = (const float*)d_in[1];
  const float* beta = (const float*)d_in[2];
  const float* delta = (const float*)d_in[3];
  const float* epsm = (const float*)d_in[4];
  const float* Wm = (const float*)d_in[5];
  const float* bm = (const float*)d_in[6];
  const float* Ws = (const float*)d_in[7];
  const float* bs = (const float*)d_in[8];
  const float* mW0 = (const float*)d_in[9];
  const float* mb0 = (const float*)d_in[10];
  const float* mW1 = (const float*)d_in[11];
  const float* mb1 = (const float*)d_in[12];
  const float* sW0 = (const float*)d_in[13];
  const float* sb0 = (const float*)d_in[14];
  const float* sW1 = (const float*)d_in[15];
  const float* sb1 = (const float*)d_in[16];
  float* out = (float*)d_out;

  float* w = (float*)d_ws;
  float* XM = w;    w += (size_t)kN * kF;   // x_mean -> later h_mean
  float* XS = w;    w += (size_t)kN * kF;   // x_std  -> later h_std
  float* Mrow = w;  w += (size_t)kN * kF;   // m -> V0tm -> V1tm
  float* CSrow = w; w += (size_t)kN * kF;   // cs -> V0ts -> V1ts
  float* WSR = w;   w += (size_t)kN * kN;   // ws_raw -> AdjT in place
  float* Wmt = w;   w += (size_t)kF * kF;
  float* Wst = w;   w += (size_t)kF * kF;
  float* mW0t = w;  w += (size_t)kF * kF;
  float* sW0t = w;  w += (size_t)kF * kF;
  float* mW1t = w;  w += (size_t)kH * kF;
  float* sW1t = w;  w += (size_t)kH * kF;
  float* sq = w;    w += kN;
  float* csum = w;  w += kN;
  float* invn = w;  w += kN;
  float* dis = w;   w += kN;

  const dim3 blk(256);
  const int nTri = (kN / 64) * (kN / 64 + 1) / 2;  // 2080

  // 0) weight transposes ([K][N] -> [N][K])
  transpose_f32<<<(kF * kF) / 256, blk, 0, stream>>>(Wm, Wmt, kF, kF);
  transpose_f32<<<(kF * kF) / 256, blk, 0, stream>>>(Ws, Wst, kF, kF);
  transpose_f32<<<(kF * kF) / 256, blk, 0, stream>>>(mW0, mW0t, kF, kF);
  transpose_f32<<<(kF * kF) / 256, blk, 0, stream>>>(sW0, sW0t, kF, kF);
  transpose_f32<<<(kF * kH) / 256, blk, 0, stream>>>(mW1, mW1t, kF, kH);
  transpose_f32<<<(kF * kH) / 256, blk, 0, stream>>>(sW1, sW1t, kF, kH);

  // 1) x_mean, x_std
  mfma_gemm<false, false><<<dim3(kF / 64, kN / 128), blk, 0, stream>>>(
      x, Wmt, XM, kN, kF, kF, nullptr, bm);
  mfma_gemm<false, false><<<dim3(kF / 64, kN / 128), blk, 0, stream>>>(
      x, Wst, XS, kN, kF, kF, nullptr, bs);

  // 2) row stats
  row_stats_kernel<<<kN, blk, 0, stream>>>(XM, XS, Mrow, CSrow, sq, csum);

  // 3) ws_raw (symmetric, triangle only)
  ws_mfma<<<nTri, blk, 0, stream>>>(Mrow, CSrow, sq, csum, WSR);

  // 4) row inverse norms
  row_invnorm_kernel<<<kN, blk, 0, stream>>>(WSR, invn);

  // 5) adjacency + in-place transpose -> AdjT
  adj_transpose<<<nTri, blk, 0, stream>>>(WSR, invn, ne, epsm, beta, delta);

  // 6) degree -> dis
  deg_dis_kernel<<<kN, blk, 0, stream>>>(WSR, dis);

  // 7) encoders
  float* V0tm = Mrow;
  float* V0ts = CSrow;
  float* hm = XM;
  float* hs = XS;
  float* V1tm = Mrow;
  float* V1ts = CSrow;

  // V0t = (dis[i] * (X @ W0))^T   [F][N]
  mfma_gemm<true, false><<<dim3(kF / 64, kN / 128), blk, 0, stream>>>(
      XM, mW0t, V0tm, kN, kF, kF, dis, nullptr);
  mfma_gemm<true, false><<<dim3(kF / 64, kN / 128), blk, 0, stream>>>(
      XS, sW0t, V0ts, kN, kF, kF, dis, nullptr);

  // h = relu(dis[j] * (AdjT @ V0t^T) + b0)   [N][F]
  mfma_gemm<false, true><<<dim3(kF / 64, kN / 128), blk, 0, stream>>>(
      WSR, V0tm, hm, kN, kF, kN, dis, mb0);
  mfma_gemm<false, true><<<dim3(kF / 64, kN / 128), blk, 0, stream>>>(
      WSR, V0ts, hs, kN, kF, kN, dis, sb0);

  // V1t = (dis[i] * (h @ W1))^T   [H][N]
  mfma_gemm<true, false><<<dim3(kH / 64, kN / 128), blk, 0, stream>>>(
      hm, mW1t, V1tm, kN, kH, kF, dis, nullptr);
  mfma_gemm<true, false><<<dim3(kH / 64, kN / 128), blk, 0, stream>>>(
      hs, sW1t, V1ts, kN, kH, kF, dis, nullptr);

  // z = relu(dis[j] * (AdjT @ V1t^T) + b1) -> d_out
  mfma_gemm<false, true><<<dim3(kH / 64, kN / 128), blk, 0, stream>>>(
      WSR, V1tm, out, kN, kH, kN, dis, mb1);
  mfma_gemm<false, true><<<dim3(kH / 64, kN / 128), blk, 0, stream>>>(
      WSR, V1ts, out + (size_t)kN * kH, kN, kH, kN, dis, sb1);
}

// Round 4
// 982.460 us; speedup vs baseline: 2.2410x; 1.5292x over previous
//
#include <hip/hip_runtime.h>
#include <cstddef>

static constexpr int kN = 4096;
static constexpr int kF = 512;
static constexpr int kH = 256;
static constexpr float kClamp = 1e-6f;

using bf16x8 = __attribute__((ext_vector_type(8))) __bf16;
using f32x4 = __attribute__((ext_vector_type(4))) float;
using ushort8 = __attribute__((ext_vector_type(8))) unsigned short;
using ushort4v = __attribute__((ext_vector_type(4))) unsigned short;

static constexpr size_t PLANE_XF = (size_t)kN * kF;    // 2M
static constexpr size_t PLANE_NN = (size_t)kN * kN;    // 16.8M
static constexpr size_t PLANE_W = (size_t)512 * 512;
static constexpr size_t PLANE_W1 = (size_t)512 * 256;
static constexpr size_t PLANE_V0 = (size_t)1024 * kN;
static constexpr size_t PLANE_H = (size_t)kN * 1024;
static constexpr size_t PLANE_V1 = (size_t)512 * kN;

__device__ __forceinline__ unsigned short f2bf(float x) {
  unsigned int u = __float_as_uint(x);
  u += 0x7fffu + ((u >> 16) & 1u);
  return (unsigned short)(u >> 16);
}
__device__ __forceinline__ float bf2f(unsigned short h) {
  return __uint_as_float(((unsigned int)h) << 16);
}
__device__ __forceinline__ void split3(float x, unsigned short& h,
                                       unsigned short& m, unsigned short& l) {
  h = f2bf(x);
  const float r1 = x - bf2f(h);
  m = f2bf(r1);
  l = f2bf(r1 - bf2f(m));
}
__device__ __forceinline__ void split3x4(const float4 v, ushort4v& h4,
                                         ushort4v& m4, ushort4v& l4) {
  unsigned short h, m, l;
  split3(v.x, h, m, l); h4.x = h; m4.x = m; l4.x = l;
  split3(v.y, h, m, l); h4.y = h; m4.y = m; l4.y = l;
  split3(v.z, h, m, l); h4.z = h; m4.z = m; l4.z = l;
  split3(v.w, h, m, l); h4.w = h; m4.w = m; l4.w = l;
}

__device__ __forceinline__ bf16x8 ldfrag(const unsigned short* p) {
  ushort8 r = *(const ushort8*)p;
  return __builtin_bit_cast(bf16x8, r);
}
__device__ __forceinline__ f32x4 mfma16(bf16x8 a, bf16x8 b, f32x4 c) {
  return __builtin_amdgcn_mfma_f32_16x16x32_bf16(a, b, c, 0, 0, 0);
}
// hh+hm+mh+mm+hl+lh, smallest-first (rel err ~2^-26)
__device__ __forceinline__ f32x4 mfma_split6(const bf16x8* a3, const bf16x8* b3,
                                             f32x4 acc) {
  acc = mfma16(a3[2], b3[0], acc);
  acc = mfma16(a3[0], b3[2], acc);
  acc = mfma16(a3[1], b3[1], acc);
  acc = mfma16(a3[1], b3[0], acc);
  acc = mfma16(a3[0], b3[1], acc);
  acc = mfma16(a3[0], b3[0], acc);
  return acc;
}

__device__ __forceinline__ void tri_map(int b, int& bi, int& bj) {
  int x = (int)((sqrtf(8.0f * (float)b + 1.0f) - 1.0f) * 0.5f);
  while ((x + 1) * (x + 2) / 2 <= b) ++x;
  while (x * (x + 1) / 2 > b) --x;
  bi = x;
  bj = b - x * (x + 1) / 2;
}

__device__ __forceinline__ float block_reduce_sum(float v, float* sbuf) {
  const int tid = threadIdx.x;
  sbuf[tid] = v;
  __syncthreads();
#pragma unroll
  for (int s = 128; s > 0; s >>= 1) {
    if (tid < s) sbuf[tid] += sbuf[tid + s];
    __syncthreads();
  }
  const float r = sbuf[0];
  __syncthreads();
  return r;
}

// ============ prep: transpose+split all 6 weights ============
// src W [512][N] row-major -> dst planes [3][N][512]: dst[p][n][k]=split_p(W[k][n])
__global__ __launch_bounds__(256) void prep_w(
    const float* s0, const float* s1, const float* s2, const float* s3,
    const float* s4, const float* s5, unsigned short* d0, unsigned short* d1,
    unsigned short* d2, unsigned short* d3, unsigned short* d4,
    unsigned short* d5) {
  const int seg = blockIdx.y;
  const float* src;
  unsigned short* dst;
  int N;
  switch (seg) {
    case 0: src = s0; dst = d0; N = 512; break;
    case 1: src = s1; dst = d1; N = 512; break;
    case 2: src = s2; dst = d2; N = 512; break;
    case 3: src = s3; dst = d3; N = 512; break;
    case 4: src = s4; dst = d4; N = 256; break;
    default: src = s5; dst = d5; N = 256; break;
  }
  const int id = blockIdx.x * 256 + threadIdx.x;
  if (id >= 512 * N) return;
  const int k = id & 511;
  const int n = id >> 9;
  const float v = src[(size_t)k * N + n];
  unsigned short h, m, l;
  split3(v, h, m, l);
  const size_t base = (size_t)n * 512 + k;
  const size_t plane = (size_t)512 * N;
  dst[base] = h;
  dst[plane + base] = m;
  dst[2 * plane + base] = l;
}

// ============ elementwise split of x ============
__global__ __launch_bounds__(256) void split_x(const float* __restrict__ x,
                                               unsigned short* __restrict__ x3) {
  const size_t id = (size_t)blockIdx.x * 256 + threadIdx.x;
  unsigned short h, m, l;
  split3(x[id], h, m, l);
  x3[id] = h;
  x3[PLANE_XF + id] = m;
  x3[2 * PLANE_XF + id] = l;
}

// ============ generic two-stream split-bf16 MFMA GEMM ============
// C[m][n] = epi( sum_k A[m][k]*B[n][k] ), A/B are 3-plane bf16.
// Stream select per block: n0 >= N1 -> use *1 pointers with local n.
// OUT: 0 = f32 row-major (Cf), 1 = split3 row-major (Cs), 2 = split3 CT (Cs,
//      addr = col*ldc + row).
template <int BM, int BN, int OUT, bool RELU>
__global__ __launch_bounds__(256) void gemm3(
    const unsigned short* __restrict__ A0, const unsigned short* __restrict__ A1,
    int lda, size_t planeA, const unsigned short* __restrict__ B0,
    const unsigned short* __restrict__ B1, int ldb, size_t planeB,
    float* __restrict__ Cf0, float* __restrict__ Cf1,
    unsigned short* __restrict__ Cs0, unsigned short* __restrict__ Cs1, int ldc,
    size_t planeC, int N1, int K, const float* __restrict__ rowScale,
    const float* __restrict__ bias0, const float* __restrict__ bias1) {
  __shared__ __align__(16) unsigned short Asl[3][BM][40];
  __shared__ __align__(16) unsigned short Bsl[3][BN][40];
  const int tid = threadIdx.x;
  const int lane = tid & 63;
  const int wave = tid >> 6;
  const int wm = wave >> 1;
  const int wn = wave & 1;
  const int m0 = blockIdx.y * BM;
  const int n0 = blockIdx.x * BN;
  const bool str1 = (n0 >= N1);
  const int nloc = str1 ? (n0 - N1) : n0;
  const unsigned short* Ab = str1 ? A1 : A0;
  const unsigned short* Bb = str1 ? B1 : B0;
  const float* bias = str1 ? bias1 : bias0;
  const int rl = lane & 15;
  const int kq = (lane >> 4) * 8;
  const int q = lane >> 4;
  constexpr int MT = BM / 32;
  constexpr int NTn = BN / 32;

  f32x4 acc[MT][NTn];
#pragma unroll
  for (int i = 0; i < MT; ++i)
#pragma unroll
    for (int j = 0; j < NTn; ++j) acc[i][j] = (f32x4){0.f, 0.f, 0.f, 0.f};

  for (int k0 = 0; k0 < K; k0 += 32) {
    constexpr int AIT = (3 * BM * 4) / 256;
#pragma unroll
    for (int it = 0; it < AIT; ++it) {
      const int c = tid + it * 256;
      const int plane = c / (BM * 4);
      const int rem = c % (BM * 4);
      const int row = rem >> 2;
      const int kc = (rem & 3) * 8;
      const ushort8 v = *(const ushort8*)(&Ab[(size_t)plane * planeA +
                                              (size_t)(m0 + row) * lda + k0 + kc]);
      *(ushort8*)(&Asl[plane][row][kc]) = v;
    }
    constexpr int BIT = (3 * BN * 4) / 256;
#pragma unroll
    for (int it = 0; it < BIT; ++it) {
      const int c = tid + it * 256;
      const int plane = c / (BN * 4);
      const int rem = c % (BN * 4);
      const int row = rem >> 2;
      const int kc = (rem & 3) * 8;
      const ushort8 v = *(const ushort8*)(&Bb[(size_t)plane * planeB +
                                              (size_t)(n0 + row - n0 + nloc + row - row) * 0 +
                                              (size_t)(nloc + row) * ldb + k0 + kc]);
      *(ushort8*)(&Bsl[plane][row][kc]) = v;
    }
    __syncthreads();

    bf16x8 af[MT][3], bfr[NTn][3];
#pragma unroll
    for (int mt = 0; mt < MT; ++mt)
#pragma unroll
      for (int t = 0; t < 3; ++t)
        af[mt][t] = ldfrag(&Asl[t][wm * (BM / 2) + mt * 16 + rl][kq]);
#pragma unroll
    for (int nt = 0; nt < NTn; ++nt)
#pragma unroll
      for (int t = 0; t < 3; ++t)
        bfr[nt][t] = ldfrag(&Bsl[t][wn * (BN / 2) + nt * 16 + rl][kq]);

#pragma unroll
    for (int mt = 0; mt < MT; ++mt)
#pragma unroll
      for (int nt = 0; nt < NTn; ++nt)
        acc[mt][nt] = mfma_split6(af[mt], bfr[nt], acc[mt][nt]);
    __syncthreads();
  }

#pragma unroll
  for (int mt = 0; mt < MT; ++mt) {
#pragma unroll
    for (int nt = 0; nt < NTn; ++nt) {
      const int colL = nloc + wn * (BN / 2) + nt * 16 + rl;
      const int row0 = m0 + wm * (BM / 2) + mt * 16 + q * 4;
      float vv[4];
#pragma unroll
      for (int r = 0; r < 4; ++r) {
        float v = acc[mt][nt][r];
        if (rowScale) v *= rowScale[row0 + r];
        if (bias) v += bias[colL];
        if (RELU) v = fmaxf(v, 0.f);
        vv[r] = v;
      }
      if (OUT == 0) {
        float* C = str1 ? Cf1 : Cf0;
#pragma unroll
        for (int r = 0; r < 4; ++r) C[(size_t)(row0 + r) * ldc + colL] = vv[r];
      } else if (OUT == 1) {
        unsigned short* C = str1 ? Cs1 : Cs0;
#pragma unroll
        for (int r = 0; r < 4; ++r) {
          unsigned short h, m, l;
          split3(vv[r], h, m, l);
          const size_t base = (size_t)(row0 + r) * ldc + colL;
          C[base] = h;
          C[planeC + base] = m;
          C[2 * planeC + base] = l;
        }
      } else {
        unsigned short* C = str1 ? Cs1 : Cs0;
        const float4 v4 = make_float4(vv[0], vv[1], vv[2], vv[3]);
        ushort4v h4, m4, l4;
        split3x4(v4, h4, m4, l4);
        const size_t base = (size_t)colL * ldc + row0;
        *(ushort4v*)(&C[base]) = h4;
        *(ushort4v*)(&C[planeC + base]) = m4;
        *(ushort4v*)(&C[2 * planeC + base]) = l4;
      }
    }
  }
}

// ============ row stats: consume XM3/XS3 planes, emit M3/CS3 planes ============
__global__ __launch_bounds__(256) void row_stats_kernel(
    const unsigned short* __restrict__ XM3, const unsigned short* __restrict__ XS3,
    unsigned short* __restrict__ M3, unsigned short* __restrict__ CS3,
    float* __restrict__ sq, float* __restrict__ csum) {
  __shared__ float sbuf[256];
  const int i = blockIdx.x;
  const int tid = threadIdx.x;
  const size_t base = (size_t)i * kF;
  const size_t i0 = base + tid, i1 = base + tid + 256;
  const float x0 = bf2f(XM3[i0]) + bf2f(XM3[PLANE_XF + i0]) + bf2f(XM3[2 * PLANE_XF + i0]);
  const float x1 = bf2f(XM3[i1]) + bf2f(XM3[PLANE_XF + i1]) + bf2f(XM3[2 * PLANE_XF + i1]);
  const float nrm = block_reduce_sum(x0 * x0 + x1 * x1, sbuf);
  const float inv = 1.0f / fmaxf(sqrtf(nrm), 1e-12f);
  const float m0 = x0 * inv, m1 = x1 * inv;
  {
    unsigned short h, m, l;
    split3(m0, h, m, l);
    M3[i0] = h; M3[PLANE_XF + i0] = m; M3[2 * PLANE_XF + i0] = l;
    split3(m1, h, m, l);
    M3[i1] = h; M3[PLANE_XF + i1] = m; M3[2 * PLANE_XF + i1] = l;
  }
  const float s2 = block_reduce_sum(m0 * m0 + m1 * m1, sbuf);
  if (tid == 0) sq[i] = s2;

  const float y0 = bf2f(XS3[i0]) + bf2f(XS3[PLANE_XF + i0]) + bf2f(XS3[2 * PLANE_XF + i0]);
  const float y1 = bf2f(XS3[i1]) + bf2f(XS3[PLANE_XF + i1]) + bf2f(XS3[2 * PLANE_XF + i1]);
  const float e0 = expf(y0);
  const float e1 = expf(y1);
  const float nrm2 = block_reduce_sum(e0 * e0 + e1 * e1, sbuf);
  const float inv2 = 1.0f / fmaxf(sqrtf(nrm2), 1e-12f);
  const float c0 = e0 * inv2, c1 = e1 * inv2;
  const float sc = block_reduce_sum(c0 + c1, sbuf);
  if (tid == 0) csum[i] = sc;
  {
    unsigned short h, m, l;
    split3(sqrtf(c0), h, m, l);
    CS3[i0] = h; CS3[PLANE_XF + i0] = m; CS3[2 * PLANE_XF + i0] = l;
    split3(sqrtf(c1), h, m, l);
    CS3[i1] = h; CS3[PLANE_XF + i1] = m; CS3[2 * PLANE_XF + i1] = l;
  }
}

// ============ symmetric dual NT-GEMM ws_raw = exp(-res) ============
__global__ __launch_bounds__(256) void ws_mfma(
    const unsigned short* __restrict__ M3, const unsigned short* __restrict__ CS3,
    const float* __restrict__ sq, const float* __restrict__ csum,
    float* __restrict__ WSR) {
  __shared__ __align__(16) unsigned short S[4][3][64][40];
  int bi, bj;
  tri_map(blockIdx.x, bi, bj);
  const int i0 = bi * 64, j0 = bj * 64;
  const int tid = threadIdx.x;
  const int lane = tid & 63;
  const int wave = tid >> 6;
  const int wm = wave >> 1, wn = wave & 1;
  const int rl = lane & 15;
  const int kq = (lane >> 4) * 8;
  const int q = lane >> 4;

  f32x4 aM[2][2], aC[2][2];
#pragma unroll
  for (int i = 0; i < 2; ++i)
#pragma unroll
    for (int j = 0; j < 2; ++j) {
      aM[i][j] = (f32x4){0.f, 0.f, 0.f, 0.f};
      aC[i][j] = (f32x4){0.f, 0.f, 0.f, 0.f};
    }

  for (int k0 = 0; k0 < kF; k0 += 32) {
#pragma unroll
    for (int it = 0; it < 12; ++it) {
      const int c = tid + it * 256;
      const int op = c / 768;
      const int rem = c % 768;
      const int plane = rem >> 8;
      const int r2 = rem & 255;
      const int row = r2 >> 2;
      const int kc = (r2 & 3) * 8;
      const unsigned short* mat = (op & 1) ? CS3 : M3;
      const int rowoff = (op < 2) ? i0 : j0;
      const ushort8 v = *(const ushort8*)(&mat[(size_t)plane * PLANE_XF +
                                               (size_t)(rowoff + row) * kF + k0 + kc]);
      *(ushort8*)(&S[op][plane][row][kc]) = v;
    }
    __syncthreads();

    bf16x8 am[2][3], ac[2][3], bm[2][3], bc[2][3];
#pragma unroll
    for (int mt = 0; mt < 2; ++mt)
#pragma unroll
      for (int t = 0; t < 3; ++t) {
        am[mt][t] = ldfrag(&S[0][t][wm * 32 + mt * 16 + rl][kq]);
        ac[mt][t] = ldfrag(&S[1][t][wm * 32 + mt * 16 + rl][kq]);
      }
#pragma unroll
    for (int nt = 0; nt < 2; ++nt)
#pragma unroll
      for (int t = 0; t < 3; ++t) {
        bm[nt][t] = ldfrag(&S[2][t][wn * 32 + nt * 16 + rl][kq]);
        bc[nt][t] = ldfrag(&S[3][t][wn * 32 + nt * 16 + rl][kq]);
      }
#pragma unroll
    for (int mt = 0; mt < 2; ++mt)
#pragma unroll
      for (int nt = 0; nt < 2; ++nt) {
        aM[mt][nt] = mfma_split6(am[mt], bm[nt], aM[mt][nt]);
        aC[mt][nt] = mfma_split6(ac[mt], bc[nt], aC[mt][nt]);
      }
    __syncthreads();
  }

#pragma unroll
  for (int mt = 0; mt < 2; ++mt) {
#pragma unroll
    for (int nt = 0; nt < 2; ++nt) {
      const int j = j0 + wn * 32 + nt * 16 + rl;
      const int ib = i0 + wm * 32 + mt * 16 + q * 4;
      const float sqj = sq[j], csj = csum[j];
      float4 vv;
      float* vp = &vv.x;
#pragma unroll
      for (int r = 0; r < 4; ++r) {
        const int i = ib + r;
        const float d2 = fmaxf(sq[i] + sqj - 2.0f * aM[mt][nt][r], 0.0f);
        const float res = d2 + csum[i] + csj - 2.0f * aC[mt][nt][r];
        const float v = expf(-res);
        vp[r] = v;
        WSR[(size_t)i * kN + j] = v;
      }
      if (bi != bj) *(float4*)(&WSR[(size_t)j * kN + ib]) = vv;
    }
  }
}

// ============ row inverse L2 norm of WSR ============
__global__ __launch_bounds__(256) void row_invnorm_kernel(
    const float* __restrict__ WSR, float* __restrict__ invn) {
  __shared__ float sbuf[256];
  const int i = blockIdx.x;
  const int tid = threadIdx.x;
  const float4* rp = (const float4*)(WSR + (size_t)i * kN);
  float s = 0.0f;
#pragma unroll
  for (int q = 0; q < (kN / 4) / 256; ++q) {
    const float4 v = rp[tid + q * 256];
    s += v.x * v.x + v.y * v.y + v.z * v.z + v.w * v.w;
  }
  s = block_reduce_sum(s, sbuf);
  if (tid == 0) invn[i] = 1.0f / fmaxf(sqrtf(s), 1e-12f);
}

// ============ adjacency: transform + transposed 3-plane split + deg partials ====
__device__ __forceinline__ float adj_val(float w, float inv, float nev, float ev,
                                         float b, float d, bool diag) {
  float t = (1.0f - b) * (w * inv) + b * nev;
  t = fminf(fmaxf(t, kClamp), 1.0f - kClamp);
  float L = logf(t / (1.0f - t));
  const float e = fminf(fmaxf(ev, kClamp), 1.0f - kClamp);
  L += logf(e / (1.0f - e));
  const float s = 1.0f / (1.0f + expf(-L));
  float v = (s > d) ? s : 0.0f;
  if (diag) v = (v > 0.0f) ? v : 1.0f;
  return v;
}

__global__ __launch_bounds__(256) void adj_transpose(
    const float* __restrict__ WSR, const float* __restrict__ invn,
    const float* __restrict__ ne, const float* __restrict__ epsm,
    const float* __restrict__ beta_p, const float* __restrict__ delta_p,
    unsigned short* __restrict__ Adj3, float* __restrict__ degp) {
  __shared__ float T0[64][65];
  __shared__ float T1[64][65];
  const float b = beta_p[0];
  const float d = delta_p[0];
  int bi, bj;
  tri_map(blockIdx.x, bi, bj);
  const int i0 = bi * 64, j0 = bj * 64;
  const int tid = threadIdx.x;
  const int rlq = tid >> 4;
  const int cq = (tid & 15) * 4;
#pragma unroll
  for (int p = 0; p < 4; ++p) {
    const int ii = p * 16 + rlq;
    {
      const size_t off = (size_t)(i0 + ii) * kN + j0 + cq;
      const float4 w4 = *(const float4*)(&WSR[off]);
      const float4 n4 = *(const float4*)(&ne[off]);
      const float4 e4 = *(const float4*)(&epsm[off]);
      const float inv = invn[i0 + ii];
      const float wv[4] = {w4.x, w4.y, w4.z, w4.w};
      const float nv[4] = {n4.x, n4.y, n4.z, n4.w};
      const float ev[4] = {e4.x, e4.y, e4.z, e4.w};
#pragma unroll
      for (int u = 0; u < 4; ++u)
        T0[ii][cq + u] =
            adj_val(wv[u], inv, nv[u], ev[u], b, d, (i0 + ii) == (j0 + cq + u));
    }
    if (bi != bj) {
      const size_t off = (size_t)(j0 + ii) * kN + i0 + cq;
      const float4 w4 = *(const float4*)(&WSR[off]);
      const float4 n4 = *(const float4*)(&ne[off]);
      const float4 e4 = *(const float4*)(&epsm[off]);
      const float inv = invn[j0 + ii];
      const float wv[4] = {w4.x, w4.y, w4.z, w4.w};
      const float nv[4] = {n4.x, n4.y, n4.z, n4.w};
      const float ev[4] = {e4.x, e4.y, e4.z, e4.w};
#pragma unroll
      for (int u = 0; u < 4; ++u)
        T1[ii][cq + u] = adj_val(wv[u], inv, nv[u], ev[u], b, d, false);
    }
  }
  __syncthreads();
  // AdjT plane writes (ushort4 along i within a row of AdjT)
#pragma unroll
  for (int p = 0; p < 4; ++p) {
    const int jj = p * 16 + rlq;
    {
      const float4 v4 = make_float4(T0[cq + 0][jj], T0[cq + 1][jj],
                                    T0[cq + 2][jj], T0[cq + 3][jj]);
      ushort4v h4, m4, l4;
      split3x4(v4, h4, m4, l4);
      const size_t base = (size_t)(j0 + jj) * kN + i0 + cq;
      *(ushort4v*)(&Adj3[base]) = h4;
      *(ushort4v*)(&Adj3[PLANE_NN + base]) = m4;
      *(ushort4v*)(&Adj3[2 * PLANE_NN + base]) = l4;
    }
    if (bi != bj) {
      const float4 v4 = make_float4(T1[cq + 0][jj], T1[cq + 1][jj],
                                    T1[cq + 2][jj], T1[cq + 3][jj]);
      ushort4v h4, m4, l4;
      split3x4(v4, h4, m4, l4);
      const size_t base = (size_t)(i0 + jj) * kN + j0 + cq;
      *(ushort4v*)(&Adj3[base]) = h4;
      *(ushort4v*)(&Adj3[PLANE_NN + base]) = m4;
      *(ushort4v*)(&Adj3[2 * PLANE_NN + base]) = l4;
    }
  }
  // deterministic degree partials: degp[slot][col] (slot = block-row of Adj)
  if (tid < 64) {
    float s = 0.0f;
#pragma unroll 8
    for (int ii = 0; ii < 64; ++ii) s += T0[ii][tid];
    degp[(size_t)bi * kN + j0 + tid] = s;
    if (bi != bj) {
      float s1 = 0.0f;
#pragma unroll 8
      for (int ii = 0; ii < 64; ++ii) s1 += T1[ii][tid];
      degp[(size_t)bj * kN + i0 + tid] = s1;
    }
  }
}

__global__ __launch_bounds__(256) void deg_dis_kernel(
    const float* __restrict__ degp, float* __restrict__ dis) {
  const int j = blockIdx.x * 256 + threadIdx.x;
  float s = 0.0f;
#pragma unroll
  for (int c = 0; c < 64; ++c) s += degp[(size_t)c * kN + j];
  dis[j] = (s > 0.0f) ? (1.0f / sqrtf(s)) : 0.0f;
}

// ============ launch ============
extern "C" void kernel_launch(void* const* d_in, const int* in_sizes, int n_in,
                              void* d_out, int out_size, void* d_ws,
                              size_t ws_size, hipStream_t stream) {
  const float* x = (const float*)d_in[0];
  const float* ne = (const float*)d_in[1];
  const float* beta = (const float*)d_in[2];
  const float* delta = (const float*)d_in[3];
  const float* epsm = (const float*)d_in[4];
  const float* Wm = (const float*)d_in[5];
  const float* bm = (const float*)d_in[6];
  const float* Ws = (const float*)d_in[7];
  const float* bs = (const float*)d_in[8];
  const float* mW0 = (const float*)d_in[9];
  const float* mb0 = (const float*)d_in[10];
  const float* mW1 = (const float*)d_in[11];
  const float* mb1 = (const float*)d_in[12];
  const float* sW0 = (const float*)d_in[13];
  const float* sb0 = (const float*)d_in[14];
  const float* sW1 = (const float*)d_in[15];
  const float* sb1 = (const float*)d_in[16];
  float* out = (float*)d_out;

  char* p = (char*)d_ws;
  float* WSR = (float*)p;            p += PLANE_NN * 4;
  unsigned short* Adj3 = (unsigned short*)p;  p += 3 * PLANE_NN * 2;
  unsigned short* x3 = (unsigned short*)p;    p += 3 * PLANE_XF * 2;  // -> V1t3
  unsigned short* XM3 = (unsigned short*)p;   p += 3 * PLANE_XF * 2;  // -> h3 (w/ XS3)
  unsigned short* XS3 = (unsigned short*)p;   p += 3 * PLANE_XF * 2;
  unsigned short* M3 = (unsigned short*)p;    p += 3 * PLANE_XF * 2;  // -> V0t3 (w/ CS3)
  unsigned short* CS3 = (unsigned short*)p;   p += 3 * PLANE_XF * 2;
  unsigned short* Wmt3 = (unsigned short*)p;  p += 3 * PLANE_W * 2;
  unsigned short* Wst3 = (unsigned short*)p;  p += 3 * PLANE_W * 2;
  unsigned short* mW0t3 = (unsigned short*)p; p += 3 * PLANE_W * 2;
  unsigned short* sW0t3 = (unsigned short*)p; p += 3 * PLANE_W * 2;
  unsigned short* mW1t3 = (unsigned short*)p; p += 3 * PLANE_W1 * 2;
  unsigned short* sW1t3 = (unsigned short*)p; p += 3 * PLANE_W1 * 2;
  float* degp = (float*)p;           p += (size_t)64 * kN * 4;
  float* sq = (float*)p;             p += kN * 4;
  float* csum = (float*)p;           p += kN * 4;
  float* invn = (float*)p;           p += kN * 4;
  float* dis = (float*)p;            p += kN * 4;

  unsigned short* V1t3 = x3;
  unsigned short* h3 = XM3;
  unsigned short* V0t3 = M3;

  const dim3 blk(256);
  const int nTri = (kN / 64) * (kN / 64 + 1) / 2;  // 2080

  // 0) weight prep + x split
  prep_w<<<dim3(1024, 6), blk, 0, stream>>>(Wm, Ws, mW0, sW0, mW1, sW1, Wmt3,
                                            Wst3, mW0t3, sW0t3, mW1t3, sW1t3);
  split_x<<<(kN * kF) / 256, blk, 0, stream>>>(x, x3);

  // 1) x_mean/x_std fused: A=x3, B=Wmt3|Wst3 -> XM3|XS3 (split planes)
  gemm3<128, 64, 1, false><<<dim3(16, 32), blk, 0, stream>>>(
      x3, x3, kF, PLANE_XF, Wmt3, Wst3, kF, PLANE_W, nullptr, nullptr, XM3, XS3,
      kF, PLANE_XF, 512, kF, nullptr, bm, bs);

  // 2) row stats -> M3/CS3 planes, sq, csum
  row_stats_kernel<<<kN, blk, 0, stream>>>(XM3, XS3, M3, CS3, sq, csum);

  // 3) ws_raw (triangle + mirror)
  ws_mfma<<<nTri, blk, 0, stream>>>(M3, CS3, sq, csum, WSR);

  // 4) row inverse norms
  row_invnorm_kernel<<<kN, blk, 0, stream>>>(WSR, invn);

  // 5) adjacency -> Adj3 (transposed planes) + deg partials
  adj_transpose<<<nTri, blk, 0, stream>>>(WSR, invn, ne, epsm, beta, delta,
                                          Adj3, degp);
  // 6) dis
  deg_dis_kernel<<<kN / 256, blk, 0, stream>>>(degp, dis);

  // 7) V0t = (dis_i * XM@W0 | dis_i * XS@W0)^T  (CT split planes [1024][4096])
  gemm3<128, 64, 2, false><<<dim3(16, 32), blk, 0, stream>>>(
      XM3, XS3, kF, PLANE_XF, mW0t3, sW0t3, kF, PLANE_W, nullptr, nullptr,
      V0t3, V0t3 + (size_t)512 * kN, kN, PLANE_V0, 512, kF, dis, nullptr,
      nullptr);

  // 8) h = relu(dis_j * AdjT@V0t + b0) -> h3 planes [4096][1024]
  gemm3<128, 64, 1, true><<<dim3(16, 32), blk, 0, stream>>>(
      Adj3, Adj3, kN, PLANE_NN, V0t3, V0t3 + (size_t)512 * kN, kN, PLANE_V0,
      nullptr, nullptr, h3, h3 + 512, 1024, PLANE_H, 512, kN, dis, mb0, sb0);

  // 9) V1t = (dis_i * h@W1)^T  (CT split planes [512][4096])
  gemm3<64, 64, 2, false><<<dim3(8, 64), blk, 0, stream>>>(
      h3, h3 + 512, 1024, PLANE_H, mW1t3, sW1t3, kF, PLANE_W1, nullptr,
      nullptr, V1t3, V1t3 + (size_t)256 * kN, kN, PLANE_V1, 256, kF, dis,
      nullptr, nullptr);

  // 10) z = relu(dis_j * AdjT@V1t + b1) -> d_out (f32)
  gemm3<64, 64, 0, true><<<dim3(8, 64), blk, 0, stream>>>(
      Adj3, Adj3, kN, PLANE_NN, V1t3, V1t3 + (size_t)256 * kN, kN, PLANE_V1,
      out, out + (size_t)kN * kH, nullptr, nullptr, kH, 0, 256, kN, dis, mb1,
      sb1);
}

// Round 5
// 752.469 us; speedup vs baseline: 2.9259x; 1.3056x over previous
//
#include <hip/hip_runtime.h>
#include <cstddef>

static constexpr int kN = 4096;
static constexpr int kF = 512;
static constexpr int kH = 256;
static constexpr float kClamp = 1e-6f;

using bf16x8 = __attribute__((ext_vector_type(8))) __bf16;
using f32x4 = __attribute__((ext_vector_type(4))) float;
using ushort8 = __attribute__((ext_vector_type(8))) unsigned short;
using ushort4v = __attribute__((ext_vector_type(4))) unsigned short;

static constexpr size_t PLANE_XF = (size_t)kN * kF;      // 2.1M
static constexpr size_t PLANE_NN = (size_t)kN * kN;      // 16.8M
static constexpr size_t PLANE_W = (size_t)512 * 512;
static constexpr size_t PLANE_W1 = (size_t)256 * 512;
static constexpr size_t PLANE_V0 = (size_t)1024 * kN;
static constexpr size_t PLANE_H = (size_t)kN * 1024;
static constexpr size_t PLANE_V1 = (size_t)512 * kN;

__device__ __forceinline__ unsigned short f2bf(float x) {
  unsigned int u = __float_as_uint(x);
  u += 0x7fffu + ((u >> 16) & 1u);
  return (unsigned short)(u >> 16);
}
__device__ __forceinline__ float bf2f(unsigned short h) {
  return __uint_as_float(((unsigned int)h) << 16);
}
__device__ __forceinline__ void split3(float x, unsigned short& h,
                                       unsigned short& m, unsigned short& l) {
  h = f2bf(x);
  const float r1 = x - bf2f(h);
  m = f2bf(r1);
  l = f2bf(r1 - bf2f(m));
}
__device__ __forceinline__ void split2(float x, unsigned short& h,
                                       unsigned short& m) {
  h = f2bf(x);
  m = f2bf(x - bf2f(h));
}
__device__ __forceinline__ void split3x4(const float4 v, ushort4v& h4,
                                         ushort4v& m4, ushort4v& l4) {
  unsigned short h, m, l;
  split3(v.x, h, m, l); h4.x = h; m4.x = m; l4.x = l;
  split3(v.y, h, m, l); h4.y = h; m4.y = m; l4.y = l;
  split3(v.z, h, m, l); h4.z = h; m4.z = m; l4.z = l;
  split3(v.w, h, m, l); h4.w = h; m4.w = m; l4.w = l;
}
__device__ __forceinline__ void split2x4(const float4 v, ushort4v& h4,
                                         ushort4v& m4) {
  unsigned short h, m;
  split2(v.x, h, m); h4.x = h; m4.x = m;
  split2(v.y, h, m); h4.y = h; m4.y = m;
  split2(v.z, h, m); h4.z = h; m4.z = m;
  split2(v.w, h, m); h4.w = h; m4.w = m;
}

__device__ __forceinline__ bf16x8 ldfrag(const unsigned short* p) {
  ushort8 r = *(const ushort8*)p;
  return __builtin_bit_cast(bf16x8, r);
}
__device__ __forceinline__ f32x4 mfma16(bf16x8 a, bf16x8 b, f32x4 c) {
  return __builtin_amdgcn_mfma_f32_16x16x32_bf16(a, b, c, 0, 0, 0);
}
// 6-product (split3): rel err ~2^-26
__device__ __forceinline__ f32x4 mfma_split6(const bf16x8* a3, const bf16x8* b3,
                                             f32x4 acc) {
  acc = mfma16(a3[2], b3[0], acc);
  acc = mfma16(a3[0], b3[2], acc);
  acc = mfma16(a3[1], b3[1], acc);
  acc = mfma16(a3[1], b3[0], acc);
  acc = mfma16(a3[0], b3[1], acc);
  acc = mfma16(a3[0], b3[0], acc);
  return acc;
}
// 4-product (full split2 x split2): rel err ~2^-17.4, random-sign
__device__ __forceinline__ f32x4 mfma_split4(const bf16x8* a2, const bf16x8* b2,
                                             f32x4 acc) {
  acc = mfma16(a2[1], b2[1], acc);
  acc = mfma16(a2[1], b2[0], acc);
  acc = mfma16(a2[0], b2[1], acc);
  acc = mfma16(a2[0], b2[0], acc);
  return acc;
}

__device__ __forceinline__ void tri_map(int b, int& bi, int& bj) {
  int x = (int)((sqrtf(8.0f * (float)b + 1.0f) - 1.0f) * 0.5f);
  while ((x + 1) * (x + 2) / 2 <= b) ++x;
  while (x * (x + 1) / 2 > b) --x;
  bi = x;
  bj = b - x * (x + 1) / 2;
}

__device__ __forceinline__ float block_reduce_sum(float v, float* sbuf) {
  const int tid = threadIdx.x;
  sbuf[tid] = v;
  __syncthreads();
#pragma unroll
  for (int s = 128; s > 0; s >>= 1) {
    if (tid < s) sbuf[tid] += sbuf[tid + s];
    __syncthreads();
  }
  const float r = sbuf[0];
  __syncthreads();
  return r;
}

// ============ prep: transpose+split weights ============
// seg 0,1: Wm,Ws [512][512] -> 3-plane transposed [3][512][512]
// seg 2,3: mW0,sW0 [512][512] -> 2-plane transposed
// seg 4,5: mW1,sW1 [512][256] -> 2-plane transposed [2][256][512]
__global__ __launch_bounds__(256) void prep_w(
    const float* s0, const float* s1, const float* s2, const float* s3,
    const float* s4, const float* s5, unsigned short* d0, unsigned short* d1,
    unsigned short* d2, unsigned short* d3, unsigned short* d4,
    unsigned short* d5) {
  const int seg = blockIdx.y;
  const float* src;
  unsigned short* dst;
  int N;
  bool tri;
  switch (seg) {
    case 0: src = s0; dst = d0; N = 512; tri = true; break;
    case 1: src = s1; dst = d1; N = 512; tri = true; break;
    case 2: src = s2; dst = d2; N = 512; tri = false; break;
    case 3: src = s3; dst = d3; N = 512; tri = false; break;
    case 4: src = s4; dst = d4; N = 256; tri = false; break;
    default: src = s5; dst = d5; N = 256; tri = false; break;
  }
  const int id = blockIdx.x * 256 + threadIdx.x;
  if (id >= 512 * N) return;
  const int k = id & 511;
  const int n = id >> 9;
  const float v = src[(size_t)k * N + n];
  const size_t base = (size_t)n * 512 + k;
  const size_t plane = (size_t)512 * N;
  if (tri) {
    unsigned short h, m, l;
    split3(v, h, m, l);
    dst[base] = h;
    dst[plane + base] = m;
    dst[2 * plane + base] = l;
  } else {
    unsigned short h, m;
    split2(v, h, m);
    dst[base] = h;
    dst[plane + base] = m;
  }
}

// ============ split x into 3 planes ============
__global__ __launch_bounds__(256) void split_x(const float* __restrict__ x,
                                               unsigned short* __restrict__ x3) {
  const size_t id = (size_t)blockIdx.x * 256 + threadIdx.x;
  unsigned short h, m, l;
  split3(x[id], h, m, l);
  x3[id] = h;
  x3[PLANE_XF + id] = m;
  x3[2 * PLANE_XF + id] = l;
}

// ============ GEMM-1 (split3, 6-product): x@Wm|Ws -> XMf|XSf (f32) ============
__global__ __launch_bounds__(256) void gemm_x(
    const unsigned short* __restrict__ A3, const unsigned short* __restrict__ B30,
    const unsigned short* __restrict__ B31, float* __restrict__ C0,
    float* __restrict__ C1, const float* __restrict__ bias0,
    const float* __restrict__ bias1) {
  constexpr int BM = 128, BN = 64, K = 512;
  __shared__ __align__(16) unsigned short Asl[3][BM][40];
  __shared__ __align__(16) unsigned short Bsl[3][BN][40];
  const int tid = threadIdx.x;
  const int lane = tid & 63;
  const int wave = tid >> 6;
  const int wm = wave >> 1, wn = wave & 1;
  const int m0 = blockIdx.y * BM;
  const int n0 = blockIdx.x * BN;
  const bool str1 = (n0 >= 512);
  const int nloc = str1 ? (n0 - 512) : n0;
  const unsigned short* Bb = str1 ? B31 : B30;
  const float* bias = str1 ? bias1 : bias0;
  float* C = str1 ? C1 : C0;
  const int rl = lane & 15;
  const int kq = (lane >> 4) * 8;
  const int q = lane >> 4;

  f32x4 acc[4][2];
#pragma unroll
  for (int i = 0; i < 4; ++i)
#pragma unroll
    for (int j = 0; j < 2; ++j) acc[i][j] = (f32x4){0.f, 0.f, 0.f, 0.f};

  for (int k0 = 0; k0 < K; k0 += 32) {
#pragma unroll
    for (int it = 0; it < 6; ++it) {
      const int c = tid + it * 256;
      const int plane = c / (BM * 4);
      const int rem = c % (BM * 4);
      const int row = rem >> 2;
      const int kc = (rem & 3) * 8;
      const ushort8 v = *(const ushort8*)(&A3[(size_t)plane * PLANE_XF +
                                              (size_t)(m0 + row) * K + k0 + kc]);
      *(ushort8*)(&Asl[plane][row][kc]) = v;
    }
#pragma unroll
    for (int it = 0; it < 3; ++it) {
      const int c = tid + it * 256;
      const int plane = c / (BN * 4);
      const int rem = c % (BN * 4);
      const int row = rem >> 2;
      const int kc = (rem & 3) * 8;
      const ushort8 v = *(const ushort8*)(&Bb[(size_t)plane * PLANE_W +
                                              (size_t)(nloc + row) * K + k0 + kc]);
      *(ushort8*)(&Bsl[plane][row][kc]) = v;
    }
    __syncthreads();
    bf16x8 af[4][3], bfr[2][3];
#pragma unroll
    for (int mt = 0; mt < 4; ++mt)
#pragma unroll
      for (int t = 0; t < 3; ++t)
        af[mt][t] = ldfrag(&Asl[t][wm * 64 + mt * 16 + rl][kq]);
#pragma unroll
    for (int nt = 0; nt < 2; ++nt)
#pragma unroll
      for (int t = 0; t < 3; ++t)
        bfr[nt][t] = ldfrag(&Bsl[t][wn * 32 + nt * 16 + rl][kq]);
#pragma unroll
    for (int mt = 0; mt < 4; ++mt)
#pragma unroll
      for (int nt = 0; nt < 2; ++nt)
        acc[mt][nt] = mfma_split6(af[mt], bfr[nt], acc[mt][nt]);
    __syncthreads();
  }
#pragma unroll
  for (int mt = 0; mt < 4; ++mt)
#pragma unroll
    for (int nt = 0; nt < 2; ++nt) {
      const int col = nloc + wn * 32 + nt * 16 + rl;
      const int row0 = m0 + wm * 64 + mt * 16 + q * 4;
      const float bv = bias[col];
#pragma unroll
      for (int r = 0; r < 4; ++r)
        C[(size_t)(row0 + r) * 512 + col] = acc[mt][nt][r] + bv;
    }
}

// ============ generic split2 4-product GEMM ============
// C[m][n] = sum_k A[m][k]*B[n][k]. blockIdx.z selects K-slice [z*K,(z+1)*K).
// OUT 2: CT split2 planes, epi rowScale. OUT 3: f32 partial Cp[z][M][ldc].
template <int BM, int BN, int OUT>
__global__ __launch_bounds__(256) void gemm2(
    const unsigned short* __restrict__ A0, const unsigned short* __restrict__ A1,
    int lda, size_t planeA, const unsigned short* __restrict__ B0,
    const unsigned short* __restrict__ B1, int ldb, size_t planeB,
    unsigned short* __restrict__ Cs0, unsigned short* __restrict__ Cs1,
    float* __restrict__ Cp, int ldc, size_t planeC, int N1, int K,
    const float* __restrict__ rowScale) {
  __shared__ __align__(16) unsigned short Asl[2][BM][40];
  __shared__ __align__(16) unsigned short Bsl[2][BN][40];
  const int tid = threadIdx.x;
  const int lane = tid & 63;
  const int wave = tid >> 6;
  const int wm = wave >> 1, wn = wave & 1;
  const int m0 = blockIdx.y * BM;
  const int n0 = blockIdx.x * BN;
  const int kOff = blockIdx.z * K;
  const bool str1 = (n0 >= N1);
  const int nloc = str1 ? (n0 - N1) : n0;
  const unsigned short* Ab = str1 ? A1 : A0;
  const unsigned short* Bb = str1 ? B1 : B0;
  const int rl = lane & 15;
  const int kq = (lane >> 4) * 8;
  const int q = lane >> 4;
  constexpr int MT = BM / 32;
  constexpr int NT = BN / 32;

  f32x4 acc[MT][NT];
#pragma unroll
  for (int i = 0; i < MT; ++i)
#pragma unroll
    for (int j = 0; j < NT; ++j) acc[i][j] = (f32x4){0.f, 0.f, 0.f, 0.f};

  for (int k0 = 0; k0 < K; k0 += 32) {
    constexpr int AIT = (2 * BM * 4) / 256;
#pragma unroll
    for (int it = 0; it < AIT; ++it) {
      const int c = tid + it * 256;
      const int plane = c / (BM * 4);
      const int rem = c % (BM * 4);
      const int row = rem >> 2;
      const int kc = (rem & 3) * 8;
      const ushort8 v = *(const ushort8*)(&Ab[(size_t)plane * planeA +
                                              (size_t)(m0 + row) * lda + kOff +
                                              k0 + kc]);
      *(ushort8*)(&Asl[plane][row][kc]) = v;
    }
    constexpr int BIT = (2 * BN * 4) / 256;
#pragma unroll
    for (int it = 0; it < BIT; ++it) {
      const int c = tid + it * 256;
      const int plane = c / (BN * 4);
      const int rem = c % (BN * 4);
      const int row = rem >> 2;
      const int kc = (rem & 3) * 8;
      const ushort8 v = *(const ushort8*)(&Bb[(size_t)plane * planeB +
                                              (size_t)(nloc + row) * ldb + kOff +
                                              k0 + kc]);
      *(ushort8*)(&Bsl[plane][row][kc]) = v;
    }
    __syncthreads();
    bf16x8 af[MT][2], bfr[NT][2];
#pragma unroll
    for (int mt = 0; mt < MT; ++mt)
#pragma unroll
      for (int t = 0; t < 2; ++t)
        af[mt][t] = ldfrag(&Asl[t][wm * (BM / 2) + mt * 16 + rl][kq]);
#pragma unroll
    for (int nt = 0; nt < NT; ++nt)
#pragma unroll
      for (int t = 0; t < 2; ++t)
        bfr[nt][t] = ldfrag(&Bsl[t][wn * (BN / 2) + nt * 16 + rl][kq]);
#pragma unroll
    for (int mt = 0; mt < MT; ++mt)
#pragma unroll
      for (int nt = 0; nt < NT; ++nt)
        acc[mt][nt] = mfma_split4(af[mt], bfr[nt], acc[mt][nt]);
    __syncthreads();
  }

#pragma unroll
  for (int mt = 0; mt < MT; ++mt) {
#pragma unroll
    for (int nt = 0; nt < NT; ++nt) {
      const int colL = nloc + wn * (BN / 2) + nt * 16 + rl;
      const int row0 = m0 + wm * (BM / 2) + mt * 16 + q * 4;
      if (OUT == 2) {
        float4 v4;
        float* vp = &v4.x;
#pragma unroll
        for (int r = 0; r < 4; ++r) {
          float v = acc[mt][nt][r];
          if (rowScale) v *= rowScale[row0 + r];
          vp[r] = v;
        }
        unsigned short* C = str1 ? Cs1 : Cs0;
        ushort4v h4, m4;
        split2x4(v4, h4, m4);
        const size_t base = (size_t)colL * ldc + row0;
        *(ushort4v*)(&C[base]) = h4;
        *(ushort4v*)(&C[planeC + base]) = m4;
      } else {
        const size_t zoff =
            (size_t)blockIdx.z * (size_t)(gridDim.y * BM) * (size_t)ldc;
#pragma unroll
        for (int r = 0; r < 4; ++r)
          Cp[zoff + (size_t)(row0 + r) * ldc + colL] = acc[mt][nt][r];
      }
    }
  }
}

// ============ row stats: XMf/XSf f32 -> M2/CS2/XM2/XS2 planes ============
__global__ __launch_bounds__(256) void row_stats(
    const float* __restrict__ XMf, const float* __restrict__ XSf,
    unsigned short* __restrict__ M2, unsigned short* __restrict__ CS2,
    unsigned short* __restrict__ XM2, unsigned short* __restrict__ XS2,
    float* __restrict__ sq, float* __restrict__ csum) {
  __shared__ float sbuf[256];
  const int i = blockIdx.x;
  const int tid = threadIdx.x;
  const size_t base = (size_t)i * kF;
  const size_t i0 = base + tid, i1 = base + tid + 256;
  const float x0 = XMf[i0], x1 = XMf[i1];
  {
    unsigned short h, m;
    split2(x0, h, m);
    XM2[i0] = h; XM2[PLANE_XF + i0] = m;
    split2(x1, h, m);
    XM2[i1] = h; XM2[PLANE_XF + i1] = m;
  }
  const float nrm = block_reduce_sum(x0 * x0 + x1 * x1, sbuf);
  const float inv = 1.0f / fmaxf(sqrtf(nrm), 1e-12f);
  const float m0 = x0 * inv, m1 = x1 * inv;
  {
    unsigned short h, m;
    split2(m0, h, m);
    M2[i0] = h; M2[PLANE_XF + i0] = m;
    split2(m1, h, m);
    M2[i1] = h; M2[PLANE_XF + i1] = m;
  }
  const float s2 = block_reduce_sum(m0 * m0 + m1 * m1, sbuf);
  if (tid == 0) sq[i] = s2;

  const float y0 = XSf[i0], y1 = XSf[i1];
  {
    unsigned short h, m;
    split2(y0, h, m);
    XS2[i0] = h; XS2[PLANE_XF + i0] = m;
    split2(y1, h, m);
    XS2[i1] = h; XS2[PLANE_XF + i1] = m;
  }
  const float e0 = expf(y0), e1 = expf(y1);
  const float nrm2 = block_reduce_sum(e0 * e0 + e1 * e1, sbuf);
  const float inv2 = 1.0f / fmaxf(sqrtf(nrm2), 1e-12f);
  const float c0 = e0 * inv2, c1 = e1 * inv2;
  const float sc = block_reduce_sum(c0 + c1, sbuf);
  if (tid == 0) csum[i] = sc;
  {
    unsigned short h, m;
    split2(sqrtf(c0), h, m);
    CS2[i0] = h; CS2[PLANE_XF + i0] = m;
    split2(sqrtf(c1), h, m);
    CS2[i1] = h; CS2[PLANE_XF + i1] = m;
  }
}

// ============ symmetric dual NT-GEMM (split2): ws_raw = exp(-res) ============
__global__ __launch_bounds__(256) void ws_mfma2(
    const unsigned short* __restrict__ M2, const unsigned short* __restrict__ CS2,
    const float* __restrict__ sq, const float* __restrict__ csum,
    float* __restrict__ WSR) {
  __shared__ __align__(16) unsigned short S[4][2][64][40];
  int bi, bj;
  tri_map(blockIdx.x, bi, bj);
  const int i0 = bi * 64, j0 = bj * 64;
  const int tid = threadIdx.x;
  const int lane = tid & 63;
  const int wave = tid >> 6;
  const int wm = wave >> 1, wn = wave & 1;
  const int rl = lane & 15;
  const int kq = (lane >> 4) * 8;
  const int q = lane >> 4;

  f32x4 aM[2][2], aC[2][2];
#pragma unroll
  for (int i = 0; i < 2; ++i)
#pragma unroll
    for (int j = 0; j < 2; ++j) {
      aM[i][j] = (f32x4){0.f, 0.f, 0.f, 0.f};
      aC[i][j] = (f32x4){0.f, 0.f, 0.f, 0.f};
    }

  for (int k0 = 0; k0 < kF; k0 += 32) {
#pragma unroll
    for (int it = 0; it < 8; ++it) {
      const int c = tid + it * 256;
      const int op = c >> 9;
      const int rem = c & 511;
      const int plane = rem >> 8;
      const int r2 = rem & 255;
      const int row = r2 >> 2;
      const int kc = (r2 & 3) * 8;
      const unsigned short* mat = (op & 1) ? CS2 : M2;
      const int rowoff = (op < 2) ? i0 : j0;
      const ushort8 v = *(const ushort8*)(&mat[(size_t)plane * PLANE_XF +
                                               (size_t)(rowoff + row) * kF + k0 +
                                               kc]);
      *(ushort8*)(&S[op][plane][row][kc]) = v;
    }
    __syncthreads();
    bf16x8 am[2][2], ac[2][2], bm[2][2], bc[2][2];
#pragma unroll
    for (int mt = 0; mt < 2; ++mt)
#pragma unroll
      for (int t = 0; t < 2; ++t) {
        am[mt][t] = ldfrag(&S[0][t][wm * 32 + mt * 16 + rl][kq]);
        ac[mt][t] = ldfrag(&S[1][t][wm * 32 + mt * 16 + rl][kq]);
      }
#pragma unroll
    for (int nt = 0; nt < 2; ++nt)
#pragma unroll
      for (int t = 0; t < 2; ++t) {
        bm[nt][t] = ldfrag(&S[2][t][wn * 32 + nt * 16 + rl][kq]);
        bc[nt][t] = ldfrag(&S[3][t][wn * 32 + nt * 16 + rl][kq]);
      }
#pragma unroll
    for (int mt = 0; mt < 2; ++mt)
#pragma unroll
      for (int nt = 0; nt < 2; ++nt) {
        aM[mt][nt] = mfma_split4(am[mt], bm[nt], aM[mt][nt]);
        aC[mt][nt] = mfma_split4(ac[mt], bc[nt], aC[mt][nt]);
      }
    __syncthreads();
  }

#pragma unroll
  for (int mt = 0; mt < 2; ++mt) {
#pragma unroll
    for (int nt = 0; nt < 2; ++nt) {
      const int j = j0 + wn * 32 + nt * 16 + rl;
      const int ib = i0 + wm * 32 + mt * 16 + q * 4;
      const float sqj = sq[j], csj = csum[j];
      float4 vv;
      float* vp = &vv.x;
#pragma unroll
      for (int r = 0; r < 4; ++r) {
        const int i = ib + r;
        const float d2 = fmaxf(sq[i] + sqj - 2.0f * aM[mt][nt][r], 0.0f);
        const float res = d2 + csum[i] + csj - 2.0f * aC[mt][nt][r];
        const float v = expf(-res);
        vp[r] = v;
        WSR[(size_t)i * kN + j] = v;
      }
      if (bi != bj) *(float4*)(&WSR[(size_t)j * kN + ib]) = vv;
    }
  }
}

// ============ row inverse L2 norm of WSR ============
__global__ __launch_bounds__(256) void row_invnorm_kernel(
    const float* __restrict__ WSR, float* __restrict__ invn) {
  __shared__ float sbuf[256];
  const int i = blockIdx.x;
  const int tid = threadIdx.x;
  const float4* rp = (const float4*)(WSR + (size_t)i * kN);
  float s = 0.0f;
#pragma unroll
  for (int q = 0; q < (kN / 4) / 256; ++q) {
    const float4 v = rp[tid + q * 256];
    s += v.x * v.x + v.y * v.y + v.z * v.z + v.w * v.w;
  }
  s = block_reduce_sum(s, sbuf);
  if (tid == 0) invn[i] = 1.0f / fmaxf(sqrtf(s), 1e-12f);
}

// ============ adjacency transform + transposed 2-plane split + deg ============
__device__ __forceinline__ float adj_val(float w, float inv, float nev, float ev,
                                         float b, float d, bool diag) {
  float t = (1.0f - b) * (w * inv) + b * nev;
  t = fminf(fmaxf(t, kClamp), 1.0f - kClamp);
  float L = logf(t / (1.0f - t));
  const float e = fminf(fmaxf(ev, kClamp), 1.0f - kClamp);
  L += logf(e / (1.0f - e));
  const float s = 1.0f / (1.0f + expf(-L));
  float v = (s > d) ? s : 0.0f;
  if (diag) v = (v > 0.0f) ? v : 1.0f;
  return v;
}

__global__ __launch_bounds__(256) void adj_transpose(
    const float* __restrict__ WSR, const float* __restrict__ invn,
    const float* __restrict__ ne, const float* __restrict__ epsm,
    const float* __restrict__ beta_p, const float* __restrict__ delta_p,
    unsigned short* __restrict__ Adj2, float* __restrict__ degp) {
  __shared__ float T0[64][65];
  __shared__ float T1[64][65];
  const float b = beta_p[0];
  const float d = delta_p[0];
  int bi, bj;
  tri_map(blockIdx.x, bi, bj);
  const int i0 = bi * 64, j0 = bj * 64;
  const int tid = threadIdx.x;
  const int rlq = tid >> 4;
  const int cq = (tid & 15) * 4;
#pragma unroll
  for (int p = 0; p < 4; ++p) {
    const int ii = p * 16 + rlq;
    {
      const size_t off = (size_t)(i0 + ii) * kN + j0 + cq;
      const float4 w4 = *(const float4*)(&WSR[off]);
      const float4 n4 = *(const float4*)(&ne[off]);
      const float4 e4 = *(const float4*)(&epsm[off]);
      const float inv = invn[i0 + ii];
      const float wv[4] = {w4.x, w4.y, w4.z, w4.w};
      const float nv[4] = {n4.x, n4.y, n4.z, n4.w};
      const float ev[4] = {e4.x, e4.y, e4.z, e4.w};
#pragma unroll
      for (int u = 0; u < 4; ++u)
        T0[ii][cq + u] =
            adj_val(wv[u], inv, nv[u], ev[u], b, d, (i0 + ii) == (j0 + cq + u));
    }
    if (bi != bj) {
      const size_t off = (size_t)(j0 + ii) * kN + i0 + cq;
      const float4 w4 = *(const float4*)(&WSR[off]);
      const float4 n4 = *(const float4*)(&ne[off]);
      const float4 e4 = *(const float4*)(&epsm[off]);
      const float inv = invn[j0 + ii];
      const float wv[4] = {w4.x, w4.y, w4.z, w4.w};
      const float nv[4] = {n4.x, n4.y, n4.z, n4.w};
      const float ev[4] = {e4.x, e4.y, e4.z, e4.w};
#pragma unroll
      for (int u = 0; u < 4; ++u)
        T1[ii][cq + u] = adj_val(wv[u], inv, nv[u], ev[u], b, d, false);
    }
  }
  __syncthreads();
#pragma unroll
  for (int p = 0; p < 4; ++p) {
    const int jj = p * 16 + rlq;
    {
      const float4 v4 = make_float4(T0[cq + 0][jj], T0[cq + 1][jj],
                                    T0[cq + 2][jj], T0[cq + 3][jj]);
      ushort4v h4, m4;
      split2x4(v4, h4, m4);
      const size_t base = (size_t)(j0 + jj) * kN + i0 + cq;
      *(ushort4v*)(&Adj2[base]) = h4;
      *(ushort4v*)(&Adj2[PLANE_NN + base]) = m4;
    }
    if (bi != bj) {
      const float4 v4 = make_float4(T1[cq + 0][jj], T1[cq + 1][jj],
                                    T1[cq + 2][jj], T1[cq + 3][jj]);
      ushort4v h4, m4;
      split2x4(v4, h4, m4);
      const size_t base = (size_t)(i0 + jj) * kN + j0 + cq;
      *(ushort4v*)(&Adj2[base]) = h4;
      *(ushort4v*)(&Adj2[PLANE_NN + base]) = m4;
    }
  }
  if (tid < 64) {
    float s = 0.0f;
#pragma unroll 8
    for (int ii = 0; ii < 64; ++ii) s += T0[ii][tid];
    degp[(size_t)bi * kN + j0 + tid] = s;
    if (bi != bj) {
      float s1 = 0.0f;
#pragma unroll 8
      for (int ii = 0; ii < 64; ++ii) s1 += T1[ii][tid];
      degp[(size_t)bj * kN + i0 + tid] = s1;
    }
  }
}

__global__ __launch_bounds__(256) void deg_dis_kernel(
    const float* __restrict__ degp, float* __restrict__ dis) {
  const int j = blockIdx.x * 256 + threadIdx.x;
  float s = 0.0f;
#pragma unroll
  for (int c = 0; c < 64; ++c) s += degp[(size_t)c * kN + j];
  dis[j] = (s > 0.0f) ? (1.0f / sqrtf(s)) : 0.0f;
}

// ============ split-K combines ============
// h2[m][c] = split2(relu(dis[m]*(hp0+hp1)[m][c] + bias(c)))
__global__ __launch_bounds__(256) void combine_h(
    const float* __restrict__ hp, const float* __restrict__ dis,
    const float* __restrict__ b0, const float* __restrict__ b1,
    unsigned short* __restrict__ h2) {
  const size_t qd = (size_t)blockIdx.x * 256 + threadIdx.x;
  const int m = (int)(qd >> 8);
  const int c0 = (int)(qd & 255) * 4;
  const size_t off = (size_t)m * 1024 + c0;
  const float4 s0 = *(const float4*)(&hp[off]);
  const float4 s1 = *(const float4*)(&hp[PLANE_H + off]);
  const float4 bv = (c0 < 512) ? *(const float4*)(&b0[c0])
                               : *(const float4*)(&b1[c0 - 512]);
  const float ds = dis[m];
  float4 v4;
  v4.x = fmaxf(ds * (s0.x + s1.x) + bv.x, 0.f);
  v4.y = fmaxf(ds * (s0.y + s1.y) + bv.y, 0.f);
  v4.z = fmaxf(ds * (s0.z + s1.z) + bv.z, 0.f);
  v4.w = fmaxf(ds * (s0.w + s1.w) + bv.w, 0.f);
  ushort4v h4, m4;
  split2x4(v4, h4, m4);
  *(ushort4v*)(&h2[off]) = h4;
  *(ushort4v*)(&h2[PLANE_H + off]) = m4;
}

// out = relu(dis[m]*sum4(zp) + bias), routed to z_mean | z_std halves
__global__ __launch_bounds__(256) void combine_z(
    const float* __restrict__ zp, const float* __restrict__ dis,
    const float* __restrict__ b0, const float* __restrict__ b1,
    float* __restrict__ out) {
  const size_t qd = (size_t)blockIdx.x * 256 + threadIdx.x;
  const int m = (int)(qd >> 7);
  const int c0 = (int)(qd & 127) * 4;
  const size_t off = (size_t)m * 512 + c0;
  constexpr size_t PZ = (size_t)kN * 512;
  const float4 s0 = *(const float4*)(&zp[off]);
  const float4 s1 = *(const float4*)(&zp[PZ + off]);
  const float4 s2 = *(const float4*)(&zp[2 * PZ + off]);
  const float4 s3 = *(const float4*)(&zp[3 * PZ + off]);
  const float4 bv = (c0 < 256) ? *(const float4*)(&b0[c0])
                               : *(const float4*)(&b1[c0 - 256]);
  const float ds = dis[m];
  float4 v4;
  v4.x = fmaxf(ds * (s0.x + s1.x + s2.x + s3.x) + bv.x, 0.f);
  v4.y = fmaxf(ds * (s0.y + s1.y + s2.y + s3.y) + bv.y, 0.f);
  v4.z = fmaxf(ds * (s0.z + s1.z + s2.z + s3.z) + bv.z, 0.f);
  v4.w = fmaxf(ds * (s0.w + s1.w + s2.w + s3.w) + bv.w, 0.f);
  float* dst = (c0 < 256) ? &out[(size_t)m * 256 + c0]
                          : &out[(size_t)kN * 256 + (size_t)m * 256 + (c0 - 256)];
  *(float4*)dst = v4;
}

// ============ launch ============
extern "C" void kernel_launch(void* const* d_in, const int* in_sizes, int n_in,
                              void* d_out, int out_size, void* d_ws,
                              size_t ws_size, hipStream_t stream) {
  const float* x = (const float*)d_in[0];
  const float* ne = (const float*)d_in[1];
  const float* beta = (const float*)d_in[2];
  const float* delta = (const float*)d_in[3];
  const float* epsm = (const float*)d_in[4];
  const float* Wm = (const float*)d_in[5];
  const float* bm = (const float*)d_in[6];
  const float* Ws = (const float*)d_in[7];
  const float* bs = (const float*)d_in[8];
  const float* mW0 = (const float*)d_in[9];
  const float* mb0 = (const float*)d_in[10];
  const float* mW1 = (const float*)d_in[11];
  const float* mb1 = (const float*)d_in[12];
  const float* sW0 = (const float*)d_in[13];
  const float* sb0 = (const float*)d_in[14];
  const float* sW1 = (const float*)d_in[15];
  const float* sb1 = (const float*)d_in[16];
  float* out = (float*)d_out;

  char* p = (char*)d_ws;
  float* WSR = (float*)p;                     p += PLANE_NN * 4;
  unsigned short* Adj2 = (unsigned short*)p;  p += 2 * PLANE_NN * 2;
  unsigned short* x3 = (unsigned short*)p;    p += 3 * PLANE_XF * 2;  // -> V1t2
  float* XMf = (float*)p;                     p += PLANE_XF * 4;
  float* XSf = (float*)p;                     p += PLANE_XF * 4;
  unsigned short* XM2 = (unsigned short*)p;   p += 2 * PLANE_XF * 2;  // -> h2
  unsigned short* XS2 = (unsigned short*)p;   p += 2 * PLANE_XF * 2;
  unsigned short* M2 = (unsigned short*)p;    p += 2 * PLANE_XF * 2;  // -> V0t2
  unsigned short* CS2 = (unsigned short*)p;   p += 2 * PLANE_XF * 2;
  float* hp = (float*)p;                      p += 2 * PLANE_H * 4;   // -> zp
  unsigned short* Wm3 = (unsigned short*)p;   p += 3 * PLANE_W * 2;
  unsigned short* Ws3 = (unsigned short*)p;   p += 3 * PLANE_W * 2;
  unsigned short* mW0t2 = (unsigned short*)p; p += 2 * PLANE_W * 2;
  unsigned short* sW0t2 = (unsigned short*)p; p += 2 * PLANE_W * 2;
  unsigned short* mW1t2 = (unsigned short*)p; p += 2 * PLANE_W1 * 2;
  unsigned short* sW1t2 = (unsigned short*)p; p += 2 * PLANE_W1 * 2;
  float* degp = (float*)p;                    p += (size_t)64 * kN * 4;
  float* sq = (float*)p;                      p += kN * 4;
  float* csum = (float*)p;                    p += kN * 4;
  float* invn = (float*)p;                    p += kN * 4;
  float* dis = (float*)p;                     p += kN * 4;

  unsigned short* V1t2 = x3;
  unsigned short* h2 = XM2;
  unsigned short* V0t2 = M2;
  float* zp = hp;

  const dim3 blk(256);
  const int nTri = (kN / 64) * (kN / 64 + 1) / 2;  // 2080
  const int BIGN = 1 << 30;

  prep_w<<<dim3(1024, 6), blk, 0, stream>>>(Wm, Ws, mW0, sW0, mW1, sW1, Wm3,
                                            Ws3, mW0t2, sW0t2, mW1t2, sW1t2);
  split_x<<<(kN * kF) / 256, blk, 0, stream>>>(x, x3);

  // 1) x_mean/x_std (split3, full precision) -> f32
  gemm_x<<<dim3(16, 32), blk, 0, stream>>>(x3, Wm3, Ws3, XMf, XSf, bm, bs);

  // 2) row stats + all split2 planes
  row_stats<<<kN, blk, 0, stream>>>(XMf, XSf, M2, CS2, XM2, XS2, sq, csum);

  // 3) ws_raw (triangle + mirror)
  ws_mfma2<<<nTri, blk, 0, stream>>>(M2, CS2, sq, csum, WSR);

  // 4) row inverse norms
  row_invnorm_kernel<<<kN, blk, 0, stream>>>(WSR, invn);

  // 5) adjacency -> Adj2 (transposed 2-plane) + deg partials
  adj_transpose<<<nTri, blk, 0, stream>>>(WSR, invn, ne, epsm, beta, delta,
                                          Adj2, degp);
  deg_dis_kernel<<<kN / 256, blk, 0, stream>>>(degp, dis);

  // 6) V0t = (dis_i * XM@W0 | XS@W0)^T  -> split2 CT planes [1024][4096]
  gemm2<128, 64, 2><<<dim3(16, 32), blk, 0, stream>>>(
      XM2, XS2, kF, PLANE_XF, mW0t2, sW0t2, kF, PLANE_W, V0t2,
      V0t2 + (size_t)512 * kN, nullptr, kN, PLANE_V0, 512, kF, dis);

  // 7) h partials (split-K=2): AdjT @ V0t
  gemm2<128, 64, 3><<<dim3(16, 32, 2), blk, 0, stream>>>(
      Adj2, Adj2, kN, PLANE_NN, V0t2, V0t2, kN, PLANE_V0, nullptr, nullptr, hp,
      1024, 0, BIGN, kN / 2, nullptr);
  combine_h<<<(int)(PLANE_H / 4 / 256), blk, 0, stream>>>(hp, dis, mb0, sb0, h2);

  // 8) V1t = (dis_i * h@W1)^T -> split2 CT planes [512][4096]
  gemm2<64, 64, 2><<<dim3(8, 64), blk, 0, stream>>>(
      h2, h2 + 512, 1024, PLANE_H, mW1t2, sW1t2, kF, PLANE_W1, V1t2,
      V1t2 + (size_t)256 * kN, nullptr, kN, PLANE_V1, 256, kF, dis);

  // 9) z partials (split-K=4): AdjT @ V1t
  gemm2<128, 64, 3><<<dim3(8, 32, 4), blk, 0, stream>>>(
      Adj2, Adj2, kN, PLANE_NN, V1t2, V1t2, kN, PLANE_V1, nullptr, nullptr, zp,
      512, 0, BIGN, kN / 4, nullptr);
  combine_z<<<(int)((size_t)kN * 512 / 4 / 256), blk, 0, stream>>>(zp, dis, mb1,
                                                                   sb1, out);
}

// Round 6
// 664.774 us; speedup vs baseline: 3.3119x; 1.1319x over previous
//
#include <hip/hip_runtime.h>
#include <cstddef>

static constexpr int kN = 4096;
static constexpr int kF = 512;
static constexpr int kH = 256;
static constexpr float kClamp = 1e-6f;

using bf16x8 = __attribute__((ext_vector_type(8))) __bf16;
using f32x4 = __attribute__((ext_vector_type(4))) float;
using ushort8 = __attribute__((ext_vector_type(8))) unsigned short;
using ushort4v = __attribute__((ext_vector_type(4))) unsigned short;

static constexpr size_t PLANE_XF = (size_t)kN * kF;      // 2.1M
static constexpr size_t PLANE_NN = (size_t)kN * kN;      // 16.8M
static constexpr size_t PLANE_W = (size_t)512 * 512;
static constexpr size_t PLANE_W1 = (size_t)256 * 512;
static constexpr size_t PLANE_V0 = (size_t)1024 * kN;
static constexpr size_t PLANE_H = (size_t)kN * 1024;
static constexpr size_t PLANE_V1 = (size_t)512 * kN;

__device__ __forceinline__ unsigned short f2bf(float x) {
  unsigned int u = __float_as_uint(x);
  u += 0x7fffu + ((u >> 16) & 1u);
  return (unsigned short)(u >> 16);
}
__device__ __forceinline__ float bf2f(unsigned short h) {
  return __uint_as_float(((unsigned int)h) << 16);
}
__device__ __forceinline__ void split3(float x, unsigned short& h,
                                       unsigned short& m, unsigned short& l) {
  h = f2bf(x);
  const float r1 = x - bf2f(h);
  m = f2bf(r1);
  l = f2bf(r1 - bf2f(m));
}
__device__ __forceinline__ void split2(float x, unsigned short& h,
                                       unsigned short& m) {
  h = f2bf(x);
  m = f2bf(x - bf2f(h));
}
__device__ __forceinline__ void split3x4(const float4 v, ushort4v& h4,
                                         ushort4v& m4, ushort4v& l4) {
  unsigned short h, m, l;
  split3(v.x, h, m, l); h4.x = h; m4.x = m; l4.x = l;
  split3(v.y, h, m, l); h4.y = h; m4.y = m; l4.y = l;
  split3(v.z, h, m, l); h4.z = h; m4.z = m; l4.z = l;
  split3(v.w, h, m, l); h4.w = h; m4.w = m; l4.w = l;
}
__device__ __forceinline__ void split2x4(const float4 v, ushort4v& h4,
                                         ushort4v& m4) {
  unsigned short h, m;
  split2(v.x, h, m); h4.x = h; m4.x = m;
  split2(v.y, h, m); h4.y = h; m4.y = m;
  split2(v.z, h, m); h4.z = h; m4.z = m;
  split2(v.w, h, m); h4.w = h; m4.w = m;
}

__device__ __forceinline__ bf16x8 ldfrag(const unsigned short* p) {
  ushort8 r = *(const ushort8*)p;
  return __builtin_bit_cast(bf16x8, r);
}
__device__ __forceinline__ f32x4 mfma16(bf16x8 a, bf16x8 b, f32x4 c) {
  return __builtin_amdgcn_mfma_f32_16x16x32_bf16(a, b, c, 0, 0, 0);
}
// 6-product (split3): rel err ~2^-26
__device__ __forceinline__ f32x4 mfma_split6(const bf16x8* a3, const bf16x8* b3,
                                             f32x4 acc) {
  acc = mfma16(a3[2], b3[0], acc);
  acc = mfma16(a3[0], b3[2], acc);
  acc = mfma16(a3[1], b3[1], acc);
  acc = mfma16(a3[1], b3[0], acc);
  acc = mfma16(a3[0], b3[1], acc);
  acc = mfma16(a3[0], b3[0], acc);
  return acc;
}

__device__ __forceinline__ void tri_map(int b, int& bi, int& bj) {
  int x = (int)((sqrtf(8.0f * (float)b + 1.0f) - 1.0f) * 0.5f);
  while ((x + 1) * (x + 2) / 2 <= b) ++x;
  while (x * (x + 1) / 2 > b) --x;
  bi = x;
  bj = b - x * (x + 1) / 2;
}

__device__ __forceinline__ float block_reduce_sum(float v, float* sbuf) {
  const int tid = threadIdx.x;
  sbuf[tid] = v;
  __syncthreads();
#pragma unroll
  for (int s = 128; s > 0; s >>= 1) {
    if (tid < s) sbuf[tid] += sbuf[tid + s];
    __syncthreads();
  }
  const float r = sbuf[0];
  __syncthreads();
  return r;
}

// ============ prep: transpose+split weights ============
__global__ __launch_bounds__(256) void prep_w(
    const float* s0, const float* s1, const float* s2, const float* s3,
    const float* s4, const float* s5, unsigned short* d0, unsigned short* d1,
    unsigned short* d2, unsigned short* d3, unsigned short* d4,
    unsigned short* d5) {
  const int seg = blockIdx.y;
  const float* src;
  unsigned short* dst;
  int N;
  bool tri;
  switch (seg) {
    case 0: src = s0; dst = d0; N = 512; tri = true; break;
    case 1: src = s1; dst = d1; N = 512; tri = true; break;
    case 2: src = s2; dst = d2; N = 512; tri = false; break;
    case 3: src = s3; dst = d3; N = 512; tri = false; break;
    case 4: src = s4; dst = d4; N = 256; tri = false; break;
    default: src = s5; dst = d5; N = 256; tri = false; break;
  }
  const int id = blockIdx.x * 256 + threadIdx.x;
  if (id >= 512 * N) return;
  const int k = id & 511;
  const int n = id >> 9;
  const float v = src[(size_t)k * N + n];
  const size_t base = (size_t)n * 512 + k;
  const size_t plane = (size_t)512 * N;
  if (tri) {
    unsigned short h, m, l;
    split3(v, h, m, l);
    dst[base] = h;
    dst[plane + base] = m;
    dst[2 * plane + base] = l;
  } else {
    unsigned short h, m;
    split2(v, h, m);
    dst[base] = h;
    dst[plane + base] = m;
  }
}

// ============ split x into 3 planes ============
__global__ __launch_bounds__(256) void split_x(const float* __restrict__ x,
                                               unsigned short* __restrict__ x3) {
  const size_t id = (size_t)blockIdx.x * 256 + threadIdx.x;
  unsigned short h, m, l;
  split3(x[id], h, m, l);
  x3[id] = h;
  x3[PLANE_XF + id] = m;
  x3[2 * PLANE_XF + id] = l;
}

// ============ GEMM-1 (split3, 6-product): x@Wm|Ws -> XMf|XSf (f32) ============
__global__ __launch_bounds__(256) void gemm_x(
    const unsigned short* __restrict__ A3, const unsigned short* __restrict__ B30,
    const unsigned short* __restrict__ B31, float* __restrict__ C0,
    float* __restrict__ C1, const float* __restrict__ bias0,
    const float* __restrict__ bias1) {
  constexpr int BM = 128, BN = 64, K = 512;
  __shared__ __align__(16) unsigned short Asl[3][BM][40];
  __shared__ __align__(16) unsigned short Bsl[3][BN][40];
  const int tid = threadIdx.x;
  const int lane = tid & 63;
  const int wave = tid >> 6;
  const int wm = wave >> 1, wn = wave & 1;
  const int m0 = blockIdx.y * BM;
  const int n0 = blockIdx.x * BN;
  const bool str1 = (n0 >= 512);
  const int nloc = str1 ? (n0 - 512) : n0;
  const unsigned short* Bb = str1 ? B31 : B30;
  const float* bias = str1 ? bias1 : bias0;
  float* C = str1 ? C1 : C0;
  const int rl = lane & 15;
  const int kq = (lane >> 4) * 8;
  const int q = lane >> 4;

  f32x4 acc[4][2];
#pragma unroll
  for (int i = 0; i < 4; ++i)
#pragma unroll
    for (int j = 0; j < 2; ++j) acc[i][j] = (f32x4){0.f, 0.f, 0.f, 0.f};

  for (int k0 = 0; k0 < K; k0 += 32) {
#pragma unroll
    for (int it = 0; it < 6; ++it) {
      const int c = tid + it * 256;
      const int plane = c / (BM * 4);
      const int rem = c % (BM * 4);
      const int row = rem >> 2;
      const int kc = (rem & 3) * 8;
      const ushort8 v = *(const ushort8*)(&A3[(size_t)plane * PLANE_XF +
                                              (size_t)(m0 + row) * K + k0 + kc]);
      *(ushort8*)(&Asl[plane][row][kc]) = v;
    }
#pragma unroll
    for (int it = 0; it < 3; ++it) {
      const int c = tid + it * 256;
      const int plane = c / (BN * 4);
      const int rem = c % (BN * 4);
      const int row = rem >> 2;
      const int kc = (rem & 3) * 8;
      const ushort8 v = *(const ushort8*)(&Bb[(size_t)plane * PLANE_W +
                                              (size_t)(nloc + row) * K + k0 + kc]);
      *(ushort8*)(&Bsl[plane][row][kc]) = v;
    }
    __syncthreads();
    bf16x8 af[4][3], bfr[2][3];
#pragma unroll
    for (int mt = 0; mt < 4; ++mt)
#pragma unroll
      for (int t = 0; t < 3; ++t)
        af[mt][t] = ldfrag(&Asl[t][wm * 64 + mt * 16 + rl][kq]);
#pragma unroll
    for (int nt = 0; nt < 2; ++nt)
#pragma unroll
      for (int t = 0; t < 3; ++t)
        bfr[nt][t] = ldfrag(&Bsl[t][wn * 32 + nt * 16 + rl][kq]);
#pragma unroll
    for (int mt = 0; mt < 4; ++mt)
#pragma unroll
      for (int nt = 0; nt < 2; ++nt)
        acc[mt][nt] = mfma_split6(af[mt], bfr[nt], acc[mt][nt]);
    __syncthreads();
  }
#pragma unroll
  for (int mt = 0; mt < 4; ++mt)
#pragma unroll
    for (int nt = 0; nt < 2; ++nt) {
      const int col = nloc + wn * 32 + nt * 16 + rl;
      const int row0 = m0 + wm * 64 + mt * 16 + q * 4;
      const float bv = bias[col];
#pragma unroll
      for (int r = 0; r < 4; ++r)
        C[(size_t)(row0 + r) * 512 + col] = acc[mt][nt][r] + bv;
    }
}

// ============ generic split2 NP-product GEMM ============
// C[m][n] = sum_k A[m][k]*B[n][k]. blockIdx.z selects K-slice [z*K,(z+1)*K).
// OUT 2: CT split2 planes + rowScale. OUT 3: f32 partial Cp[z][M][ldc].
// NP=3: hh+hm+mh (residual ~2^-17.5 rel); NP=4: + mm.
template <int BM, int BN, int OUT, int NP>
__global__ __launch_bounds__(256) void gemm2(
    const unsigned short* __restrict__ A0, const unsigned short* __restrict__ A1,
    int lda, size_t planeA, const unsigned short* __restrict__ B0,
    const unsigned short* __restrict__ B1, int ldb, size_t planeB,
    unsigned short* __restrict__ Cs0, unsigned short* __restrict__ Cs1,
    float* __restrict__ Cp, int ldc, size_t planeC, int N1, int K,
    const float* __restrict__ rowScale) {
  __shared__ __align__(16) unsigned short Asl[2][BM][40];
  __shared__ __align__(16) unsigned short Bsl[2][BN][40];
  const int tid = threadIdx.x;
  const int lane = tid & 63;
  const int wave = tid >> 6;
  const int wm = wave >> 1, wn = wave & 1;
  const int m0 = blockIdx.y * BM;
  const int n0 = blockIdx.x * BN;
  const int kOff = blockIdx.z * K;
  const bool str1 = (n0 >= N1);
  const int nloc = str1 ? (n0 - N1) : n0;
  const unsigned short* Ab = str1 ? A1 : A0;
  const unsigned short* Bb = str1 ? B1 : B0;
  const int rl = lane & 15;
  const int kq = (lane >> 4) * 8;
  const int q = lane >> 4;
  constexpr int MT = BM / 32;
  constexpr int NT = BN / 32;

  f32x4 acc[MT][NT];
#pragma unroll
  for (int i = 0; i < MT; ++i)
#pragma unroll
    for (int j = 0; j < NT; ++j) acc[i][j] = (f32x4){0.f, 0.f, 0.f, 0.f};

  for (int k0 = 0; k0 < K; k0 += 32) {
    constexpr int AIT = (2 * BM * 4) / 256;
#pragma unroll
    for (int it = 0; it < AIT; ++it) {
      const int c = tid + it * 256;
      const int plane = c / (BM * 4);
      const int rem = c % (BM * 4);
      const int row = rem >> 2;
      const int kc = (rem & 3) * 8;
      const ushort8 v = *(const ushort8*)(&Ab[(size_t)plane * planeA +
                                              (size_t)(m0 + row) * lda + kOff +
                                              k0 + kc]);
      *(ushort8*)(&Asl[plane][row][kc]) = v;
    }
    constexpr int BIT = (2 * BN * 4) / 256;
#pragma unroll
    for (int it = 0; it < BIT; ++it) {
      const int c = tid + it * 256;
      const int plane = c / (BN * 4);
      const int rem = c % (BN * 4);
      const int row = rem >> 2;
      const int kc = (rem & 3) * 8;
      const ushort8 v = *(const ushort8*)(&Bb[(size_t)plane * planeB +
                                              (size_t)(nloc + row) * ldb + kOff +
                                              k0 + kc]);
      *(ushort8*)(&Bsl[plane][row][kc]) = v;
    }
    __syncthreads();
    bf16x8 af[MT][2];
#pragma unroll
    for (int mt = 0; mt < MT; ++mt)
#pragma unroll
      for (int t = 0; t < 2; ++t)
        af[mt][t] = ldfrag(&Asl[t][wm * (BM / 2) + mt * 16 + rl][kq]);
#pragma unroll
    for (int nt = 0; nt < NT; ++nt) {
      const bf16x8 b0 = ldfrag(&Bsl[0][wn * (BN / 2) + nt * 16 + rl][kq]);
      const bf16x8 b1 = ldfrag(&Bsl[1][wn * (BN / 2) + nt * 16 + rl][kq]);
#pragma unroll
      for (int mt = 0; mt < MT; ++mt) {
        if (NP == 4) acc[mt][nt] = mfma16(af[mt][1], b1, acc[mt][nt]);
        acc[mt][nt] = mfma16(af[mt][1], b0, acc[mt][nt]);
        acc[mt][nt] = mfma16(af[mt][0], b1, acc[mt][nt]);
        acc[mt][nt] = mfma16(af[mt][0], b0, acc[mt][nt]);
      }
    }
    __syncthreads();
  }

#pragma unroll
  for (int mt = 0; mt < MT; ++mt) {
#pragma unroll
    for (int nt = 0; nt < NT; ++nt) {
      const int colL = nloc + wn * (BN / 2) + nt * 16 + rl;
      const int row0 = m0 + wm * (BM / 2) + mt * 16 + q * 4;
      if (OUT == 2) {
        float4 v4;
        float* vp = &v4.x;
#pragma unroll
        for (int r = 0; r < 4; ++r) {
          float v = acc[mt][nt][r];
          if (rowScale) v *= rowScale[row0 + r];
          vp[r] = v;
        }
        unsigned short* C = str1 ? Cs1 : Cs0;
        ushort4v h4, m4;
        split2x4(v4, h4, m4);
        const size_t base = (size_t)colL * ldc + row0;
        *(ushort4v*)(&C[base]) = h4;
        *(ushort4v*)(&C[planeC + base]) = m4;
      } else {
        const size_t zoff =
            (size_t)blockIdx.z * (size_t)(gridDim.y * BM) * (size_t)ldc;
#pragma unroll
        for (int r = 0; r < 4; ++r)
          Cp[zoff + (size_t)(row0 + r) * ldc + colL] = acc[mt][nt][r];
      }
    }
  }
}

// ============ row stats: XMf/XSf f32 -> M2/CS2/XM2/XS2 planes ============
__global__ __launch_bounds__(256) void row_stats(
    const float* __restrict__ XMf, const float* __restrict__ XSf,
    unsigned short* __restrict__ M2, unsigned short* __restrict__ CS2,
    unsigned short* __restrict__ XM2, unsigned short* __restrict__ XS2,
    float* __restrict__ sq, float* __restrict__ csum) {
  __shared__ float sbuf[256];
  const int i = blockIdx.x;
  const int tid = threadIdx.x;
  const size_t base = (size_t)i * kF;
  const size_t i0 = base + tid, i1 = base + tid + 256;
  const float x0 = XMf[i0], x1 = XMf[i1];
  {
    unsigned short h, m;
    split2(x0, h, m);
    XM2[i0] = h; XM2[PLANE_XF + i0] = m;
    split2(x1, h, m);
    XM2[i1] = h; XM2[PLANE_XF + i1] = m;
  }
  const float nrm = block_reduce_sum(x0 * x0 + x1 * x1, sbuf);
  const float inv = 1.0f / fmaxf(sqrtf(nrm), 1e-12f);
  const float m0 = x0 * inv, m1 = x1 * inv;
  {
    unsigned short h, m;
    split2(m0, h, m);
    M2[i0] = h; M2[PLANE_XF + i0] = m;
    split2(m1, h, m);
    M2[i1] = h; M2[PLANE_XF + i1] = m;
  }
  const float s2 = block_reduce_sum(m0 * m0 + m1 * m1, sbuf);
  if (tid == 0) sq[i] = s2;

  const float y0 = XSf[i0], y1 = XSf[i1];
  {
    unsigned short h, m;
    split2(y0, h, m);
    XS2[i0] = h; XS2[PLANE_XF + i0] = m;
    split2(y1, h, m);
    XS2[i1] = h; XS2[PLANE_XF + i1] = m;
  }
  const float e0 = expf(y0), e1 = expf(y1);
  const float nrm2 = block_reduce_sum(e0 * e0 + e1 * e1, sbuf);
  const float inv2 = 1.0f / fmaxf(sqrtf(nrm2), 1e-12f);
  const float c0 = e0 * inv2, c1 = e1 * inv2;
  const float sc = block_reduce_sum(c0 + c1, sbuf);
  if (tid == 0) csum[i] = sc;
  {
    unsigned short h, m;
    split2(sqrtf(c0), h, m);
    CS2[i0] = h; CS2[PLANE_XF + i0] = m;
    split2(sqrtf(c1), h, m);
    CS2[i1] = h; CS2[PLANE_XF + i1] = m;
  }
}

// ============ symmetric dual NT-GEMM (split2, 3-prod): ws_raw = exp(-res) ====
__global__ __launch_bounds__(256) void ws_mfma2(
    const unsigned short* __restrict__ M2, const unsigned short* __restrict__ CS2,
    const float* __restrict__ sq, const float* __restrict__ csum,
    float* __restrict__ WSR) {
  __shared__ __align__(16) unsigned short S[4][2][64][40];
  int bi, bj;
  tri_map(blockIdx.x, bi, bj);
  const int i0 = bi * 64, j0 = bj * 64;
  const int tid = threadIdx.x;
  const int lane = tid & 63;
  const int wave = tid >> 6;
  const int wm = wave >> 1, wn = wave & 1;
  const int rl = lane & 15;
  const int kq = (lane >> 4) * 8;
  const int q = lane >> 4;

  f32x4 aM[2][2], aC[2][2];
#pragma unroll
  for (int i = 0; i < 2; ++i)
#pragma unroll
    for (int j = 0; j < 2; ++j) {
      aM[i][j] = (f32x4){0.f, 0.f, 0.f, 0.f};
      aC[i][j] = (f32x4){0.f, 0.f, 0.f, 0.f};
    }

  for (int k0 = 0; k0 < kF; k0 += 32) {
#pragma unroll
    for (int it = 0; it < 8; ++it) {
      const int c = tid + it * 256;
      const int op = c >> 9;
      const int rem = c & 511;
      const int plane = rem >> 8;
      const int r2 = rem & 255;
      const int row = r2 >> 2;
      const int kc = (r2 & 3) * 8;
      const unsigned short* mat = (op & 1) ? CS2 : M2;
      const int rowoff = (op < 2) ? i0 : j0;
      const ushort8 v = *(const ushort8*)(&mat[(size_t)plane * PLANE_XF +
                                               (size_t)(rowoff + row) * kF + k0 +
                                               kc]);
      *(ushort8*)(&S[op][plane][row][kc]) = v;
    }
    __syncthreads();
    bf16x8 am[2][2], ac[2][2], bm[2][2], bc[2][2];
#pragma unroll
    for (int mt = 0; mt < 2; ++mt)
#pragma unroll
      for (int t = 0; t < 2; ++t) {
        am[mt][t] = ldfrag(&S[0][t][wm * 32 + mt * 16 + rl][kq]);
        ac[mt][t] = ldfrag(&S[1][t][wm * 32 + mt * 16 + rl][kq]);
      }
#pragma unroll
    for (int nt = 0; nt < 2; ++nt)
#pragma unroll
      for (int t = 0; t < 2; ++t) {
        bm[nt][t] = ldfrag(&S[2][t][wn * 32 + nt * 16 + rl][kq]);
        bc[nt][t] = ldfrag(&S[3][t][wn * 32 + nt * 16 + rl][kq]);
      }
#pragma unroll
    for (int mt = 0; mt < 2; ++mt)
#pragma unroll
      for (int nt = 0; nt < 2; ++nt) {
        aM[mt][nt] = mfma16(am[mt][1], bm[nt][0], aM[mt][nt]);
        aM[mt][nt] = mfma16(am[mt][0], bm[nt][1], aM[mt][nt]);
        aM[mt][nt] = mfma16(am[mt][0], bm[nt][0], aM[mt][nt]);
        aC[mt][nt] = mfma16(ac[mt][1], bc[nt][0], aC[mt][nt]);
        aC[mt][nt] = mfma16(ac[mt][0], bc[nt][1], aC[mt][nt]);
        aC[mt][nt] = mfma16(ac[mt][0], bc[nt][0], aC[mt][nt]);
      }
    __syncthreads();
  }

#pragma unroll
  for (int mt = 0; mt < 2; ++mt) {
#pragma unroll
    for (int nt = 0; nt < 2; ++nt) {
      const int j = j0 + wn * 32 + nt * 16 + rl;
      const int ib = i0 + wm * 32 + mt * 16 + q * 4;
      const float sqj = sq[j], csj = csum[j];
      float4 vv;
      float* vp = &vv.x;
#pragma unroll
      for (int r = 0; r < 4; ++r) {
        const int i = ib + r;
        const float d2 = fmaxf(sq[i] + sqj - 2.0f * aM[mt][nt][r], 0.0f);
        const float res = d2 + csum[i] + csj - 2.0f * aC[mt][nt][r];
        const float v = expf(-res);
        vp[r] = v;
        WSR[(size_t)i * kN + j] = v;
      }
      if (bi != bj) *(float4*)(&WSR[(size_t)j * kN + ib]) = vv;
    }
  }
}

// ============ row inverse L2 norm of WSR ============
__global__ __launch_bounds__(256) void row_invnorm_kernel(
    const float* __restrict__ WSR, float* __restrict__ invn) {
  __shared__ float sbuf[256];
  const int i = blockIdx.x;
  const int tid = threadIdx.x;
  const float4* rp = (const float4*)(WSR + (size_t)i * kN);
  float s = 0.0f;
#pragma unroll
  for (int q = 0; q < (kN / 4) / 256; ++q) {
    const float4 v = rp[tid + q * 256];
    s += v.x * v.x + v.y * v.y + v.z * v.z + v.w * v.w;
  }
  s = block_reduce_sum(s, sbuf);
  if (tid == 0) invn[i] = 1.0f / fmaxf(sqrtf(s), 1e-12f);
}

// ============ adjacency transform + transposed 2-plane split + deg ============
__device__ __forceinline__ float adj_val(float w, float inv, float nev, float ev,
                                         float b, float d, bool diag) {
  float t = (1.0f - b) * (w * inv) + b * nev;
  t = fminf(fmaxf(t, kClamp), 1.0f - kClamp);
  float L = logf(t / (1.0f - t));
  const float e = fminf(fmaxf(ev, kClamp), 1.0f - kClamp);
  L += logf(e / (1.0f - e));
  const float s = 1.0f / (1.0f + expf(-L));
  float v = (s > d) ? s : 0.0f;
  if (diag) v = (v > 0.0f) ? v : 1.0f;
  return v;
}

__global__ __launch_bounds__(256) void adj_transpose(
    const float* __restrict__ WSR, const float* __restrict__ invn,
    const float* __restrict__ ne, const float* __restrict__ epsm,
    const float* __restrict__ beta_p, const float* __restrict__ delta_p,
    unsigned short* __restrict__ Adj2, float* __restrict__ degp) {
  __shared__ float T0[64][65];
  __shared__ float T1[64][65];
  const float b = beta_p[0];
  const float d = delta_p[0];
  int bi, bj;
  tri_map(blockIdx.x, bi, bj);
  const int i0 = bi * 64, j0 = bj * 64;
  const int tid = threadIdx.x;
  const int rlq = tid >> 4;
  const int cq = (tid & 15) * 4;
#pragma unroll
  for (int p = 0; p < 4; ++p) {
    const int ii = p * 16 + rlq;
    {
      const size_t off = (size_t)(i0 + ii) * kN + j0 + cq;
      const float4 w4 = *(const float4*)(&WSR[off]);
      const float4 n4 = *(const float4*)(&ne[off]);
      const float4 e4 = *(const float4*)(&epsm[off]);
      const float inv = invn[i0 + ii];
      const float wv[4] = {w4.x, w4.y, w4.z, w4.w};
      const float nv[4] = {n4.x, n4.y, n4.z, n4.w};
      const float ev[4] = {e4.x, e4.y, e4.z, e4.w};
#pragma unroll
      for (int u = 0; u < 4; ++u)
        T0[ii][cq + u] =
            adj_val(wv[u], inv, nv[u], ev[u], b, d, (i0 + ii) == (j0 + cq + u));
    }
    if (bi != bj) {
      const size_t off = (size_t)(j0 + ii) * kN + i0 + cq;
      const float4 w4 = *(const float4*)(&WSR[off]);
      const float4 n4 = *(const float4*)(&ne[off]);
      const float4 e4 = *(const float4*)(&epsm[off]);
      const float inv = invn[j0 + ii];
      const float wv[4] = {w4.x, w4.y, w4.z, w4.w};
      const float nv[4] = {n4.x, n4.y, n4.z, n4.w};
      const float ev[4] = {e4.x, e4.y, e4.z, e4.w};
#pragma unroll
      for (int u = 0; u < 4; ++u)
        T1[ii][cq + u] = adj_val(wv[u], inv, nv[u], ev[u], b, d, false);
    }
  }
  __syncthreads();
#pragma unroll
  for (int p = 0; p < 4; ++p) {
    const int jj = p * 16 + rlq;
    {
      const float4 v4 = make_float4(T0[cq + 0][jj], T0[cq + 1][jj],
                                    T0[cq + 2][jj], T0[cq + 3][jj]);
      ushort4v h4, m4;
      split2x4(v4, h4, m4);
      const size_t base = (size_t)(j0 + jj) * kN + i0 + cq;
      *(ushort4v*)(&Adj2[base]) = h4;
      *(ushort4v*)(&Adj2[PLANE_NN + base]) = m4;
    }
    if (bi != bj) {
      const float4 v4 = make_float4(T1[cq + 0][jj], T1[cq + 1][jj],
                                    T1[cq + 2][jj], T1[cq + 3][jj]);
      ushort4v h4, m4;
      split2x4(v4, h4, m4);
      const size_t base = (size_t)(i0 + jj) * kN + j0 + cq;
      *(ushort4v*)(&Adj2[base]) = h4;
      *(ushort4v*)(&Adj2[PLANE_NN + base]) = m4;
    }
  }
  if (tid < 64) {
    float s = 0.0f;
#pragma unroll 8
    for (int ii = 0; ii < 64; ++ii) s += T0[ii][tid];
    degp[(size_t)bi * kN + j0 + tid] = s;
    if (bi != bj) {
      float s1 = 0.0f;
#pragma unroll 8
      for (int ii = 0; ii < 64; ++ii) s1 += T1[ii][tid];
      degp[(size_t)bj * kN + i0 + tid] = s1;
    }
  }
}

__global__ __launch_bounds__(256) void deg_dis_kernel(
    const float* __restrict__ degp, float* __restrict__ dis) {
  const int j = blockIdx.x * 256 + threadIdx.x;
  float s = 0.0f;
#pragma unroll
  for (int c = 0; c < 64; ++c) s += degp[(size_t)c * kN + j];
  dis[j] = (s > 0.0f) ? (1.0f / sqrtf(s)) : 0.0f;
}

// ============ split-K combines ============
__global__ __launch_bounds__(256) void combine_h(
    const float* __restrict__ hp, const float* __restrict__ dis,
    const float* __restrict__ b0, const float* __restrict__ b1,
    unsigned short* __restrict__ h2) {
  const size_t qd = (size_t)blockIdx.x * 256 + threadIdx.x;
  const int m = (int)(qd >> 8);
  const int c0 = (int)(qd & 255) * 4;
  const size_t off = (size_t)m * 1024 + c0;
  const float4 s0 = *(const float4*)(&hp[off]);
  const float4 s1 = *(const float4*)(&hp[PLANE_H + off]);
  const float4 bv = (c0 < 512) ? *(const float4*)(&b0[c0])
                               : *(const float4*)(&b1[c0 - 512]);
  const float ds = dis[m];
  float4 v4;
  v4.x = fmaxf(ds * (s0.x + s1.x) + bv.x, 0.f);
  v4.y = fmaxf(ds * (s0.y + s1.y) + bv.y, 0.f);
  v4.z = fmaxf(ds * (s0.z + s1.z) + bv.z, 0.f);
  v4.w = fmaxf(ds * (s0.w + s1.w) + bv.w, 0.f);
  ushort4v h4, m4;
  split2x4(v4, h4, m4);
  *(ushort4v*)(&h2[off]) = h4;
  *(ushort4v*)(&h2[PLANE_H + off]) = m4;
}

__global__ __launch_bounds__(256) void combine_z(
    const float* __restrict__ zp, const float* __restrict__ dis,
    const float* __restrict__ b0, const float* __restrict__ b1,
    float* __restrict__ out) {
  const size_t qd = (size_t)blockIdx.x * 256 + threadIdx.x;
  const int m = (int)(qd >> 7);
  const int c0 = (int)(qd & 127) * 4;
  const size_t off = (size_t)m * 512 + c0;
  constexpr size_t PZ = (size_t)kN * 512;
  const float4 s0 = *(const float4*)(&zp[off]);
  const float4 s1 = *(const float4*)(&zp[PZ + off]);
  const float4 s2 = *(const float4*)(&zp[2 * PZ + off]);
  const float4 s3 = *(const float4*)(&zp[3 * PZ + off]);
  const float4 bv = (c0 < 256) ? *(const float4*)(&b0[c0])
                               : *(const float4*)(&b1[c0 - 256]);
  const float ds = dis[m];
  float4 v4;
  v4.x = fmaxf(ds * (s0.x + s1.x + s2.x + s3.x) + bv.x, 0.f);
  v4.y = fmaxf(ds * (s0.y + s1.y + s2.y + s3.y) + bv.y, 0.f);
  v4.z = fmaxf(ds * (s0.z + s1.z + s2.z + s3.z) + bv.z, 0.f);
  v4.w = fmaxf(ds * (s0.w + s1.w + s2.w + s3.w) + bv.w, 0.f);
  float* dst = (c0 < 256) ? &out[(size_t)m * 256 + c0]
                          : &out[(size_t)kN * 256 + (size_t)m * 256 + (c0 - 256)];
  *(float4*)dst = v4;
}

// ============ launch ============
extern "C" void kernel_launch(void* const* d_in, const int* in_sizes, int n_in,
                              void* d_out, int out_size, void* d_ws,
                              size_t ws_size, hipStream_t stream) {
  const float* x = (const float*)d_in[0];
  const float* ne = (const float*)d_in[1];
  const float* beta = (const float*)d_in[2];
  const float* delta = (const float*)d_in[3];
  const float* epsm = (const float*)d_in[4];
  const float* Wm = (const float*)d_in[5];
  const float* bm = (const float*)d_in[6];
  const float* Ws = (const float*)d_in[7];
  const float* bs = (const float*)d_in[8];
  const float* mW0 = (const float*)d_in[9];
  const float* mb0 = (const float*)d_in[10];
  const float* mW1 = (const float*)d_in[11];
  const float* mb1 = (const float*)d_in[12];
  const float* sW0 = (const float*)d_in[13];
  const float* sb0 = (const float*)d_in[14];
  const float* sW1 = (const float*)d_in[15];
  const float* sb1 = (const float*)d_in[16];
  float* out = (float*)d_out;

  char* p = (char*)d_ws;
  float* WSR = (float*)p;                     p += PLANE_NN * 4;
  unsigned short* Adj2 = (unsigned short*)p;  p += 2 * PLANE_NN * 2;
  unsigned short* x3 = (unsigned short*)p;    p += 3 * PLANE_XF * 2;  // -> V1t2
  float* XMf = (float*)p;                     p += PLANE_XF * 4;
  float* XSf = (float*)p;                     p += PLANE_XF * 4;
  unsigned short* XM2 = (unsigned short*)p;   p += 2 * PLANE_XF * 2;  // -> h2
  unsigned short* XS2 = (unsigned short*)p;   p += 2 * PLANE_XF * 2;
  unsigned short* M2 = (unsigned short*)p;    p += 2 * PLANE_XF * 2;  // -> V0t2
  unsigned short* CS2 = (unsigned short*)p;   p += 2 * PLANE_XF * 2;
  float* hp = (float*)p;                      p += 2 * PLANE_H * 4;   // -> zp
  unsigned short* Wm3 = (unsigned short*)p;   p += 3 * PLANE_W * 2;
  unsigned short* Ws3 = (unsigned short*)p;   p += 3 * PLANE_W * 2;
  unsigned short* mW0t2 = (unsigned short*)p; p += 2 * PLANE_W * 2;
  unsigned short* sW0t2 = (unsigned short*)p; p += 2 * PLANE_W * 2;
  unsigned short* mW1t2 = (unsigned short*)p; p += 2 * PLANE_W1 * 2;
  unsigned short* sW1t2 = (unsigned short*)p; p += 2 * PLANE_W1 * 2;
  float* degp = (float*)p;                    p += (size_t)64 * kN * 4;
  float* sq = (float*)p;                      p += kN * 4;
  float* csum = (float*)p;                    p += kN * 4;
  float* invn = (float*)p;                    p += kN * 4;
  float* dis = (float*)p;                     p += kN * 4;

  unsigned short* V1t2 = x3;
  unsigned short* h2 = XM2;
  unsigned short* V0t2 = M2;
  float* zp = hp;

  const dim3 blk(256);
  const int nTri = (kN / 64) * (kN / 64 + 1) / 2;  // 2080
  const int BIGN = 1 << 30;

  prep_w<<<dim3(1024, 6), blk, 0, stream>>>(Wm, Ws, mW0, sW0, mW1, sW1, Wm3,
                                            Ws3, mW0t2, sW0t2, mW1t2, sW1t2);
  split_x<<<(kN * kF) / 256, blk, 0, stream>>>(x, x3);

  // 1) x_mean/x_std (split3, full precision) -> f32
  gemm_x<<<dim3(16, 32), blk, 0, stream>>>(x3, Wm3, Ws3, XMf, XSf, bm, bs);

  // 2) row stats + all split2 planes
  row_stats<<<kN, blk, 0, stream>>>(XMf, XSf, M2, CS2, XM2, XS2, sq, csum);

  // 3) ws_raw (triangle + mirror)
  ws_mfma2<<<nTri, blk, 0, stream>>>(M2, CS2, sq, csum, WSR);

  // 4) row inverse norms
  row_invnorm_kernel<<<kN, blk, 0, stream>>>(WSR, invn);

  // 5) adjacency -> Adj2 (transposed 2-plane) + deg partials
  adj_transpose<<<nTri, blk, 0, stream>>>(WSR, invn, ne, epsm, beta, delta,
                                          Adj2, degp);
  deg_dis_kernel<<<kN / 256, blk, 0, stream>>>(degp, dis);

  // 6) V0t = (dis_i * XM@W0 | XS@W0)^T  -> split2 CT planes [1024][4096]
  gemm2<128, 64, 2, 3><<<dim3(16, 32), blk, 0, stream>>>(
      XM2, XS2, kF, PLANE_XF, mW0t2, sW0t2, kF, PLANE_W, V0t2,
      V0t2 + (size_t)512 * kN, nullptr, kN, PLANE_V0, 512, kF, dis);

  // 7) h partials (split-K=2, 128x128 tiles): AdjT @ V0t
  gemm2<128, 128, 3, 3><<<dim3(8, 32, 2), blk, 0, stream>>>(
      Adj2, Adj2, kN, PLANE_NN, V0t2, V0t2, kN, PLANE_V0, nullptr, nullptr, hp,
      1024, 0, BIGN, kN / 2, nullptr);
  combine_h<<<(int)(PLANE_H / 4 / 256), blk, 0, stream>>>(hp, dis, mb0, sb0, h2);

  // 8) V1t = (dis_i * h@W1)^T -> split2 CT planes [512][4096]
  gemm2<64, 64, 2, 3><<<dim3(8, 64), blk, 0, stream>>>(
      h2, h2 + 512, 1024, PLANE_H, mW1t2, sW1t2, kF, PLANE_W1, V1t2,
      V1t2 + (size_t)256 * kN, nullptr, kN, PLANE_V1, 256, kF, dis);

  // 9) z partials (split-K=4, 128x128 tiles): AdjT @ V1t
  gemm2<128, 128, 3, 3><<<dim3(4, 32, 4), blk, 0, stream>>>(
      Adj2, Adj2, kN, PLANE_NN, V1t2, V1t2, kN, PLANE_V1, nullptr, nullptr, zp,
      512, 0, BIGN, kN / 4, nullptr);
  combine_z<<<(int)((size_t)kN * 512 / 4 / 256), blk, 0, stream>>>(zp, dis, mb1,
                                                                   sb1, out);
}

// Round 8
// 636.192 us; speedup vs baseline: 3.4607x; 1.0449x over previous
//
#include <hip/hip_runtime.h>
#include <cstddef>

static constexpr int kN = 4096;
static constexpr int kF = 512;
static constexpr int kH = 256;
static constexpr float kClamp = 1e-6f;

using bf16x8 = __attribute__((ext_vector_type(8))) __bf16;
using f32x4 = __attribute__((ext_vector_type(4))) float;
using ushort8 = __attribute__((ext_vector_type(8))) unsigned short;
using ushort4v = __attribute__((ext_vector_type(4))) unsigned short;

static constexpr size_t PLANE_XF = (size_t)kN * kF;      // 2.1M
static constexpr size_t PLANE_NN = (size_t)kN * kN;      // 16.8M
static constexpr size_t PLANE_W = (size_t)512 * 512;
static constexpr size_t PLANE_W1 = (size_t)256 * 512;
static constexpr size_t PLANE_V0 = (size_t)1024 * kN;
static constexpr size_t PLANE_H = (size_t)kN * 1024;
static constexpr size_t PLANE_V1 = (size_t)512 * kN;

__device__ __forceinline__ unsigned short f2bf(float x) {
  unsigned int u = __float_as_uint(x);
  u += 0x7fffu + ((u >> 16) & 1u);
  return (unsigned short)(u >> 16);
}
__device__ __forceinline__ float bf2f(unsigned short h) {
  return __uint_as_float(((unsigned int)h) << 16);
}
__device__ __forceinline__ void split3(float x, unsigned short& h,
                                       unsigned short& m, unsigned short& l) {
  h = f2bf(x);
  const float r1 = x - bf2f(h);
  m = f2bf(r1);
  l = f2bf(r1 - bf2f(m));
}
__device__ __forceinline__ void split2(float x, unsigned short& h,
                                       unsigned short& m) {
  h = f2bf(x);
  m = f2bf(x - bf2f(h));
}
__device__ __forceinline__ void split2x4(const float4 v, ushort4v& h4,
                                         ushort4v& m4) {
  unsigned short h, m;
  split2(v.x, h, m); h4.x = h; m4.x = m;
  split2(v.y, h, m); h4.y = h; m4.y = m;
  split2(v.z, h, m); h4.z = h; m4.z = m;
  split2(v.w, h, m); h4.w = h; m4.w = m;
}

__device__ __forceinline__ bf16x8 ldfrag(const unsigned short* p) {
  ushort8 r = *(const ushort8*)p;
  return __builtin_bit_cast(bf16x8, r);
}
__device__ __forceinline__ f32x4 mfma16(bf16x8 a, bf16x8 b, f32x4 c) {
  return __builtin_amdgcn_mfma_f32_16x16x32_bf16(a, b, c, 0, 0, 0);
}
// 6-product (split3): rel err ~2^-26
__device__ __forceinline__ f32x4 mfma_split6(const bf16x8* a3, const bf16x8* b3,
                                             f32x4 acc) {
  acc = mfma16(a3[2], b3[0], acc);
  acc = mfma16(a3[0], b3[2], acc);
  acc = mfma16(a3[1], b3[1], acc);
  acc = mfma16(a3[1], b3[0], acc);
  acc = mfma16(a3[0], b3[1], acc);
  acc = mfma16(a3[0], b3[0], acc);
  return acc;
}

__device__ __forceinline__ void tri_map(int b, int& bi, int& bj) {
  int x = (int)((sqrtf(8.0f * (float)b + 1.0f) - 1.0f) * 0.5f);
  while ((x + 1) * (x + 2) / 2 <= b) ++x;
  while (x * (x + 1) / 2 > b) --x;
  bi = x;
  bj = b - x * (x + 1) / 2;
}

__device__ __forceinline__ float block_reduce_sum(float v, float* sbuf) {
  const int tid = threadIdx.x;
  sbuf[tid] = v;
  __syncthreads();
#pragma unroll
  for (int s = 128; s > 0; s >>= 1) {
    if (tid < s) sbuf[tid] += sbuf[tid + s];
    __syncthreads();
  }
  const float r = sbuf[0];
  __syncthreads();
  return r;
}

// ============ prep: transpose+split weights ============
__global__ __launch_bounds__(256) void prep_w(
    const float* s0, const float* s1, const float* s2, const float* s3,
    const float* s4, const float* s5, unsigned short* d0, unsigned short* d1,
    unsigned short* d2, unsigned short* d3, unsigned short* d4,
    unsigned short* d5) {
  const int seg = blockIdx.y;
  const float* src;
  unsigned short* dst;
  int N;
  bool tri;
  switch (seg) {
    case 0: src = s0; dst = d0; N = 512; tri = true; break;
    case 1: src = s1; dst = d1; N = 512; tri = true; break;
    case 2: src = s2; dst = d2; N = 512; tri = false; break;
    case 3: src = s3; dst = d3; N = 512; tri = false; break;
    case 4: src = s4; dst = d4; N = 256; tri = false; break;
    default: src = s5; dst = d5; N = 256; tri = false; break;
  }
  const int id = blockIdx.x * 256 + threadIdx.x;
  if (id >= 512 * N) return;
  const int k = id & 511;
  const int n = id >> 9;
  const float v = src[(size_t)k * N + n];
  const size_t base = (size_t)n * 512 + k;
  const size_t plane = (size_t)512 * N;
  if (tri) {
    unsigned short h, m, l;
    split3(v, h, m, l);
    dst[base] = h;
    dst[plane + base] = m;
    dst[2 * plane + base] = l;
  } else {
    unsigned short h, m;
    split2(v, h, m);
    dst[base] = h;
    dst[plane + base] = m;
  }
}

// ============ split x into 3 planes ============
__global__ __launch_bounds__(256) void split_x(const float* __restrict__ x,
                                               unsigned short* __restrict__ x3) {
  const size_t id = (size_t)blockIdx.x * 256 + threadIdx.x;
  unsigned short h, m, l;
  split3(x[id], h, m, l);
  x3[id] = h;
  x3[PLANE_XF + id] = m;
  x3[2 * PLANE_XF + id] = l;
}

// ============ GEMM-1 (split3, 6-product): x@Wm|Ws -> XMf|XSf (f32) ============
__global__ __launch_bounds__(256) void gemm_x(
    const unsigned short* __restrict__ A3, const unsigned short* __restrict__ B30,
    const unsigned short* __restrict__ B31, float* __restrict__ C0,
    float* __restrict__ C1, const float* __restrict__ bias0,
    const float* __restrict__ bias1) {
  constexpr int BM = 128, BN = 64, K = 512;
  __shared__ __align__(16) unsigned short Asl[3][BM][40];
  __shared__ __align__(16) unsigned short Bsl[3][BN][40];
  const int tid = threadIdx.x;
  const int lane = tid & 63;
  const int wave = tid >> 6;
  const int wm = wave >> 1, wn = wave & 1;
  const int m0 = blockIdx.y * BM;
  const int n0 = blockIdx.x * BN;
  const bool str1 = (n0 >= 512);
  const int nloc = str1 ? (n0 - 512) : n0;
  const unsigned short* Bb = str1 ? B31 : B30;
  const float* bias = str1 ? bias1 : bias0;
  float* C = str1 ? C1 : C0;
  const int rl = lane & 15;
  const int kq = (lane >> 4) * 8;
  const int q = lane >> 4;

  f32x4 acc[4][2];
#pragma unroll
  for (int i = 0; i < 4; ++i)
#pragma unroll
    for (int j = 0; j < 2; ++j) acc[i][j] = (f32x4){0.f, 0.f, 0.f, 0.f};

  for (int k0 = 0; k0 < K; k0 += 32) {
#pragma unroll
    for (int it = 0; it < 6; ++it) {
      const int c = tid + it * 256;
      const int plane = c / (BM * 4);
      const int rem = c % (BM * 4);
      const int row = rem >> 2;
      const int kc = (rem & 3) * 8;
      const ushort8 v = *(const ushort8*)(&A3[(size_t)plane * PLANE_XF +
                                              (size_t)(m0 + row) * K + k0 + kc]);
      *(ushort8*)(&Asl[plane][row][kc]) = v;
    }
#pragma unroll
    for (int it = 0; it < 3; ++it) {
      const int c = tid + it * 256;
      const int plane = c / (BN * 4);
      const int rem = c % (BN * 4);
      const int row = rem >> 2;
      const int kc = (rem & 3) * 8;
      const ushort8 v = *(const ushort8*)(&Bb[(size_t)plane * PLANE_W +
                                              (size_t)(nloc + row) * K + k0 + kc]);
      *(ushort8*)(&Bsl[plane][row][kc]) = v;
    }
    __syncthreads();
    bf16x8 af[4][3], bfr[2][3];
#pragma unroll
    for (int mt = 0; mt < 4; ++mt)
#pragma unroll
      for (int t = 0; t < 3; ++t)
        af[mt][t] = ldfrag(&Asl[t][wm * 64 + mt * 16 + rl][kq]);
#pragma unroll
    for (int nt = 0; nt < 2; ++nt)
#pragma unroll
      for (int t = 0; t < 3; ++t)
        bfr[nt][t] = ldfrag(&Bsl[t][wn * 32 + nt * 16 + rl][kq]);
#pragma unroll
    for (int mt = 0; mt < 4; ++mt)
#pragma unroll
      for (int nt = 0; nt < 2; ++nt)
        acc[mt][nt] = mfma_split6(af[mt], bfr[nt], acc[mt][nt]);
    __syncthreads();
  }
#pragma unroll
  for (int mt = 0; mt < 4; ++mt)
#pragma unroll
    for (int nt = 0; nt < 2; ++nt) {
      const int col = nloc + wn * 32 + nt * 16 + rl;
      const int row0 = m0 + wm * 64 + mt * 16 + q * 4;
      const float bv = bias[col];
#pragma unroll
      for (int r = 0; r < 4; ++r)
        C[(size_t)(row0 + r) * 512 + col] = acc[mt][nt][r] + bv;
    }
}

// ============ split2 3-product GEMM, CT-split2 output (small GEMMs) ============
template <int BM, int BN>
__global__ __launch_bounds__(256) void gemm2ct(
    const unsigned short* __restrict__ A0, const unsigned short* __restrict__ A1,
    int lda, size_t planeA, const unsigned short* __restrict__ B0,
    const unsigned short* __restrict__ B1, int ldb, size_t planeB,
    unsigned short* __restrict__ Cs0, unsigned short* __restrict__ Cs1, int ldc,
    size_t planeC, int N1, int K, const float* __restrict__ rowScale) {
  __shared__ __align__(16) unsigned short Asl[2][BM][40];
  __shared__ __align__(16) unsigned short Bsl[2][BN][40];
  const int tid = threadIdx.x;
  const int lane = tid & 63;
  const int wave = tid >> 6;
  const int wm = wave >> 1, wn = wave & 1;
  const int m0 = blockIdx.y * BM;
  const int n0 = blockIdx.x * BN;
  const bool str1 = (n0 >= N1);
  const int nloc = str1 ? (n0 - N1) : n0;
  const unsigned short* Ab = str1 ? A1 : A0;
  const unsigned short* Bb = str1 ? B1 : B0;
  const int rl = lane & 15;
  const int kq = (lane >> 4) * 8;
  const int q = lane >> 4;
  constexpr int MT = BM / 32;
  constexpr int NT = BN / 32;

  f32x4 acc[MT][NT];
#pragma unroll
  for (int i = 0; i < MT; ++i)
#pragma unroll
    for (int j = 0; j < NT; ++j) acc[i][j] = (f32x4){0.f, 0.f, 0.f, 0.f};

  for (int k0 = 0; k0 < K; k0 += 32) {
    constexpr int AIT = (2 * BM * 4) / 256;
#pragma unroll
    for (int it = 0; it < AIT; ++it) {
      const int c = tid + it * 256;
      const int plane = c / (BM * 4);
      const int rem = c % (BM * 4);
      const int row = rem >> 2;
      const int kc = (rem & 3) * 8;
      const ushort8 v = *(const ushort8*)(&Ab[(size_t)plane * planeA +
                                              (size_t)(m0 + row) * lda + k0 + kc]);
      *(ushort8*)(&Asl[plane][row][kc]) = v;
    }
    constexpr int BIT = (2 * BN * 4) / 256;
#pragma unroll
    for (int it = 0; it < BIT; ++it) {
      const int c = tid + it * 256;
      const int plane = c / (BN * 4);
      const int rem = c % (BN * 4);
      const int row = rem >> 2;
      const int kc = (rem & 3) * 8;
      const ushort8 v = *(const ushort8*)(&Bb[(size_t)plane * planeB +
                                              (size_t)(nloc + row) * ldb + k0 + kc]);
      *(ushort8*)(&Bsl[plane][row][kc]) = v;
    }
    __syncthreads();
    bf16x8 af[MT][2];
#pragma unroll
    for (int mt = 0; mt < MT; ++mt)
#pragma unroll
      for (int t = 0; t < 2; ++t)
        af[mt][t] = ldfrag(&Asl[t][wm * (BM / 2) + mt * 16 + rl][kq]);
#pragma unroll
    for (int nt = 0; nt < NT; ++nt) {
      const bf16x8 b0 = ldfrag(&Bsl[0][wn * (BN / 2) + nt * 16 + rl][kq]);
      const bf16x8 b1 = ldfrag(&Bsl[1][wn * (BN / 2) + nt * 16 + rl][kq]);
#pragma unroll
      for (int mt = 0; mt < MT; ++mt) {
        acc[mt][nt] = mfma16(af[mt][1], b0, acc[mt][nt]);
        acc[mt][nt] = mfma16(af[mt][0], b1, acc[mt][nt]);
        acc[mt][nt] = mfma16(af[mt][0], b0, acc[mt][nt]);
      }
    }
    __syncthreads();
  }

#pragma unroll
  for (int mt = 0; mt < MT; ++mt) {
#pragma unroll
    for (int nt = 0; nt < NT; ++nt) {
      const int colL = nloc + wn * (BN / 2) + nt * 16 + rl;
      const int row0 = m0 + wm * (BM / 2) + mt * 16 + q * 4;
      float4 v4;
      float* vp = &v4.x;
#pragma unroll
      for (int r = 0; r < 4; ++r) {
        float v = acc[mt][nt][r];
        if (rowScale) v *= rowScale[row0 + r];
        vp[r] = v;
      }
      unsigned short* C = str1 ? Cs1 : Cs0;
      ushort4v h4, m4;
      split2x4(v4, h4, m4);
      const size_t base = (size_t)colL * ldc + row0;
      *(ushort4v*)(&C[base]) = h4;
      *(ushort4v*)(&C[planeC + base]) = m4;
    }
  }
}

// ============ split2 3-product GEMM, split-K partials, XCD-swizzled ============
// 1-D grid of 8*GX*GYP*GZ blocks. xcd = id&7 owns m-band [xcd*GYP*BM ...).
// x (n-tile) fastest, then y-in-band, then z (K-phase). Cp[z][Mtot][ldc].
template <int BM, int BN, int GX, int GYP, int GZ>
__global__ __launch_bounds__(256) void gemm2k(
    const unsigned short* __restrict__ A, int lda, size_t planeA,
    const unsigned short* __restrict__ B, int ldb, size_t planeB,
    float* __restrict__ Cp, int ldc, int Mtot, int Ksl) {
  __shared__ __align__(16) unsigned short Asl[2][BM][40];
  __shared__ __align__(16) unsigned short Bsl[2][BN][40];
  const int lin = blockIdx.x;
  const int xcd = lin & 7;
  const int s = lin >> 3;
  constexpr int per = GX * GYP;
  const int z = s / per;
  const int r = s - z * per;
  const int bx = r % GX;
  const int by = xcd * GYP + r / GX;
  const int m0 = by * BM;
  const int n0 = bx * BN;
  const int kOff = z * Ksl;

  const int tid = threadIdx.x;
  const int lane = tid & 63;
  const int wave = tid >> 6;
  const int wm = wave >> 1, wn = wave & 1;
  const int rl = lane & 15;
  const int kq = (lane >> 4) * 8;
  const int q = lane >> 4;
  constexpr int MT = BM / 32;
  constexpr int NT = BN / 32;

  f32x4 acc[MT][NT];
#pragma unroll
  for (int i = 0; i < MT; ++i)
#pragma unroll
    for (int j = 0; j < NT; ++j) acc[i][j] = (f32x4){0.f, 0.f, 0.f, 0.f};

  for (int k0 = 0; k0 < Ksl; k0 += 32) {
    constexpr int AIT = (2 * BM * 4) / 256;
#pragma unroll
    for (int it = 0; it < AIT; ++it) {
      const int c = tid + it * 256;
      const int plane = c / (BM * 4);
      const int rem = c % (BM * 4);
      const int row = rem >> 2;
      const int kc = (rem & 3) * 8;
      const ushort8 v = *(const ushort8*)(&A[(size_t)plane * planeA +
                                             (size_t)(m0 + row) * lda + kOff +
                                             k0 + kc]);
      *(ushort8*)(&Asl[plane][row][kc]) = v;
    }
    constexpr int BIT = (2 * BN * 4) / 256;
#pragma unroll
    for (int it = 0; it < BIT; ++it) {
      const int c = tid + it * 256;
      const int plane = c / (BN * 4);
      const int rem = c % (BN * 4);
      const int row = rem >> 2;
      const int kc = (rem & 3) * 8;
      const ushort8 v = *(const ushort8*)(&B[(size_t)plane * planeB +
                                             (size_t)(n0 + row) * ldb + kOff +
                                             k0 + kc]);
      *(ushort8*)(&Bsl[plane][row][kc]) = v;
    }
    __syncthreads();
    bf16x8 af[MT][2];
#pragma unroll
    for (int mt = 0; mt < MT; ++mt)
#pragma unroll
      for (int t = 0; t < 2; ++t)
        af[mt][t] = ldfrag(&Asl[t][wm * (BM / 2) + mt * 16 + rl][kq]);
#pragma unroll
    for (int nt = 0; nt < NT; ++nt) {
      const bf16x8 b0 = ldfrag(&Bsl[0][wn * (BN / 2) + nt * 16 + rl][kq]);
      const bf16x8 b1 = ldfrag(&Bsl[1][wn * (BN / 2) + nt * 16 + rl][kq]);
#pragma unroll
      for (int mt = 0; mt < MT; ++mt) {
        acc[mt][nt] = mfma16(af[mt][1], b0, acc[mt][nt]);
        acc[mt][nt] = mfma16(af[mt][0], b1, acc[mt][nt]);
        acc[mt][nt] = mfma16(af[mt][0], b0, acc[mt][nt]);
      }
    }
    __syncthreads();
  }

  const size_t zoff = (size_t)z * (size_t)Mtot * (size_t)ldc;
#pragma unroll
  for (int mt = 0; mt < MT; ++mt) {
#pragma unroll
    for (int nt = 0; nt < NT; ++nt) {
      const int colL = n0 + wn * (BN / 2) + nt * 16 + rl;
      const int row0 = m0 + wm * (BM / 2) + mt * 16 + q * 4;
#pragma unroll
      for (int r = 0; r < 4; ++r)
        Cp[zoff + (size_t)(row0 + r) * ldc + colL] = acc[mt][nt][r];
    }
  }
}

// ============ row stats: XMf/XSf f32 -> M2/CS2/XM2/XS2 planes ============
__global__ __launch_bounds__(256) void row_stats(
    const float* __restrict__ XMf, const float* __restrict__ XSf,
    unsigned short* __restrict__ M2, unsigned short* __restrict__ CS2,
    unsigned short* __restrict__ XM2, unsigned short* __restrict__ XS2,
    float* __restrict__ sq, float* __restrict__ csum) {
  __shared__ float sbuf[256];
  const int i = blockIdx.x;
  const int tid = threadIdx.x;
  const size_t base = (size_t)i * kF;
  const size_t i0 = base + tid, i1 = base + tid + 256;
  const float x0 = XMf[i0], x1 = XMf[i1];
  {
    unsigned short h, m;
    split2(x0, h, m);
    XM2[i0] = h; XM2[PLANE_XF + i0] = m;
    split2(x1, h, m);
    XM2[i1] = h; XM2[PLANE_XF + i1] = m;
  }
  const float nrm = block_reduce_sum(x0 * x0 + x1 * x1, sbuf);
  const float inv = 1.0f / fmaxf(sqrtf(nrm), 1e-12f);
  const float m0 = x0 * inv, m1 = x1 * inv;
  {
    unsigned short h, m;
    split2(m0, h, m);
    M2[i0] = h; M2[PLANE_XF + i0] = m;
    split2(m1, h, m);
    M2[i1] = h; M2[PLANE_XF + i1] = m;
  }
  const float s2 = block_reduce_sum(m0 * m0 + m1 * m1, sbuf);
  if (tid == 0) sq[i] = s2;

  const float y0 = XSf[i0], y1 = XSf[i1];
  {
    unsigned short h, m;
    split2(y0, h, m);
    XS2[i0] = h; XS2[PLANE_XF + i0] = m;
    split2(y1, h, m);
    XS2[i1] = h; XS2[PLANE_XF + i1] = m;
  }
  const float e0 = expf(y0), e1 = expf(y1);
  const float nrm2 = block_reduce_sum(e0 * e0 + e1 * e1, sbuf);
  const float inv2 = 1.0f / fmaxf(sqrtf(nrm2), 1e-12f);
  const float c0 = e0 * inv2, c1 = e1 * inv2;
  const float sc = block_reduce_sum(c0 + c1, sbuf);
  if (tid == 0) csum[i] = sc;
  {
    unsigned short h, m;
    split2(sqrtf(c0), h, m);
    CS2[i0] = h; CS2[PLANE_XF + i0] = m;
    split2(sqrtf(c1), h, m);
    CS2[i1] = h; CS2[PLANE_XF + i1] = m;
  }
}

// ============ symmetric dual NT-GEMM (split2, 3-prod): ws_raw = exp(-res) ====
__global__ __launch_bounds__(256) void ws_mfma2(
    const unsigned short* __restrict__ M2, const unsigned short* __restrict__ CS2,
    const float* __restrict__ sq, const float* __restrict__ csum,
    float* __restrict__ WSR) {
  __shared__ __align__(16) unsigned short S[4][2][64][40];
  int bi, bj;
  tri_map(blockIdx.x, bi, bj);
  const int i0 = bi * 64, j0 = bj * 64;
  const int tid = threadIdx.x;
  const int lane = tid & 63;
  const int wave = tid >> 6;
  const int wm = wave >> 1, wn = wave & 1;
  const int rl = lane & 15;
  const int kq = (lane >> 4) * 8;
  const int q = lane >> 4;

  f32x4 aM[2][2], aC[2][2];
#pragma unroll
  for (int i = 0; i < 2; ++i)
#pragma unroll
    for (int j = 0; j < 2; ++j) {
      aM[i][j] = (f32x4){0.f, 0.f, 0.f, 0.f};
      aC[i][j] = (f32x4){0.f, 0.f, 0.f, 0.f};
    }

  for (int k0 = 0; k0 < kF; k0 += 32) {
#pragma unroll
    for (int it = 0; it < 8; ++it) {
      const int c = tid + it * 256;
      const int op = c >> 9;
      const int rem = c & 511;
      const int plane = rem >> 8;
      const int r2 = rem & 255;
      const int row = r2 >> 2;
      const int kc = (r2 & 3) * 8;
      const unsigned short* mat = (op & 1) ? CS2 : M2;
      const int rowoff = (op < 2) ? i0 : j0;
      const ushort8 v = *(const ushort8*)(&mat[(size_t)plane * PLANE_XF +
                                               (size_t)(rowoff + row) * kF + k0 +
                                               kc]);
      *(ushort8*)(&S[op][plane][row][kc]) = v;
    }
    __syncthreads();
    bf16x8 am[2][2], ac[2][2], bm[2][2], bc[2][2];
#pragma unroll
    for (int mt = 0; mt < 2; ++mt)
#pragma unroll
      for (int t = 0; t < 2; ++t) {
        am[mt][t] = ldfrag(&S[0][t][wm * 32 + mt * 16 + rl][kq]);
        ac[mt][t] = ldfrag(&S[1][t][wm * 32 + mt * 16 + rl][kq]);
      }
#pragma unroll
    for (int nt = 0; nt < 2; ++nt)
#pragma unroll
      for (int t = 0; t < 2; ++t) {
        bm[nt][t] = ldfrag(&S[2][t][wn * 32 + nt * 16 + rl][kq]);
        bc[nt][t] = ldfrag(&S[3][t][wn * 32 + nt * 16 + rl][kq]);
      }
#pragma unroll
    for (int mt = 0; mt < 2; ++mt)
#pragma unroll
      for (int nt = 0; nt < 2; ++nt) {
        aM[mt][nt] = mfma16(am[mt][1], bm[nt][0], aM[mt][nt]);
        aM[mt][nt] = mfma16(am[mt][0], bm[nt][1], aM[mt][nt]);
        aM[mt][nt] = mfma16(am[mt][0], bm[nt][0], aM[mt][nt]);
        aC[mt][nt] = mfma16(ac[mt][1], bc[nt][0], aC[mt][nt]);
        aC[mt][nt] = mfma16(ac[mt][0], bc[nt][1], aC[mt][nt]);
        aC[mt][nt] = mfma16(ac[mt][0], bc[nt][0], aC[mt][nt]);
      }
    __syncthreads();
  }

#pragma unroll
  for (int mt = 0; mt < 2; ++mt) {
#pragma unroll
    for (int nt = 0; nt < 2; ++nt) {
      const int j = j0 + wn * 32 + nt * 16 + rl;
      const int ib = i0 + wm * 32 + mt * 16 + q * 4;
      const float sqj = sq[j], csj = csum[j];
      float4 vv;
      float* vp = &vv.x;
#pragma unroll
      for (int r = 0; r < 4; ++r) {
        const int i = ib + r;
        const float d2 = fmaxf(sq[i] + sqj - 2.0f * aM[mt][nt][r], 0.0f);
        const float res = d2 + csum[i] + csj - 2.0f * aC[mt][nt][r];
        const float v = expf(-res);
        vp[r] = v;
        WSR[(size_t)i * kN + j] = v;
      }
      if (bi != bj) *(float4*)(&WSR[(size_t)j * kN + ib]) = vv;
    }
  }
}

// ============ row inverse L2 norm of WSR ============
__global__ __launch_bounds__(256) void row_invnorm_kernel(
    const float* __restrict__ WSR, float* __restrict__ invn) {
  __shared__ float sbuf[256];
  const int i = blockIdx.x;
  const int tid = threadIdx.x;
  const float4* rp = (const float4*)(WSR + (size_t)i * kN);
  float s = 0.0f;
#pragma unroll
  for (int q = 0; q < (kN / 4) / 256; ++q) {
    const float4 v = rp[tid + q * 256];
    s += v.x * v.x + v.y * v.y + v.z * v.z + v.w * v.w;
  }
  s = block_reduce_sum(s, sbuf);
  if (tid == 0) invn[i] = 1.0f / fmaxf(sqrtf(s), 1e-12f);
}

// ============ adjacency transform + transposed 2-plane split + deg ============
__device__ __forceinline__ float adj_val(float w, float inv, float nev, float ev,
                                         float b, float d, bool diag) {
  float t = (1.0f - b) * (w * inv) + b * nev;
  t = fminf(fmaxf(t, kClamp), 1.0f - kClamp);
  float L = logf(t / (1.0f - t));
  const float e = fminf(fmaxf(ev, kClamp), 1.0f - kClamp);
  L += logf(e / (1.0f - e));
  const float s = 1.0f / (1.0f + expf(-L));
  float v = (s > d) ? s : 0.0f;
  if (diag) v = (v > 0.0f) ? v : 1.0f;
  return v;
}

__global__ __launch_bounds__(256) void adj_transpose(
    const float* __restrict__ WSR, const float* __restrict__ invn,
    const float* __restrict__ ne, const float* __restrict__ epsm,
    const float* __restrict__ beta_p, const float* __restrict__ delta_p,
    unsigned short* __restrict__ Adj2, float* __restrict__ degp) {
  __shared__ float T0[64][65];
  __shared__ float T1[64][65];
  const float b = beta_p[0];
  const float d = delta_p[0];
  int bi, bj;
  tri_map(blockIdx.x, bi, bj);
  const int i0 = bi * 64, j0 = bj * 64;
  const int tid = threadIdx.x;
  const int rlq = tid >> 4;
  const int cq = (tid & 15) * 4;
#pragma unroll
  for (int p = 0; p < 4; ++p) {
    const int ii = p * 16 + rlq;
    {
      const size_t off = (size_t)(i0 + ii) * kN + j0 + cq;
      const float4 w4 = *(const float4*)(&WSR[off]);
      const float4 n4 = *(const float4*)(&ne[off]);
      const float4 e4 = *(const float4*)(&epsm[off]);
      const float inv = invn[i0 + ii];
      const float wv[4] = {w4.x, w4.y, w4.z, w4.w};
      const float nv[4] = {n4.x, n4.y, n4.z, n4.w};
      const float ev[4] = {e4.x, e4.y, e4.z, e4.w};
#pragma unroll
      for (int u = 0; u < 4; ++u)
        T0[ii][cq + u] =
            adj_val(wv[u], inv, nv[u], ev[u], b, d, (i0 + ii) == (j0 + cq + u));
    }
    if (bi != bj) {
      const size_t off = (size_t)(j0 + ii) * kN + i0 + cq;
      const float4 w4 = *(const float4*)(&WSR[off]);
      const float4 n4 = *(const float4*)(&ne[off]);
      const float4 e4 = *(const float4*)(&epsm[off]);
      const float inv = invn[j0 + ii];
      const float wv[4] = {w4.x, w4.y, w4.z, w4.w};
      const float nv[4] = {n4.x, n4.y, n4.z, n4.w};
      const float ev[4] = {e4.x, e4.y, e4.z, e4.w};
#pragma unroll
      for (int u = 0; u < 4; ++u)
        T1[ii][cq + u] = adj_val(wv[u], inv, nv[u], ev[u], b, d, false);
    }
  }
  __syncthreads();
#pragma unroll
  for (int p = 0; p < 4; ++p) {
    const int jj = p * 16 + rlq;
    {
      const float4 v4 = make_float4(T0[cq + 0][jj], T0[cq + 1][jj],
                                    T0[cq + 2][jj], T0[cq + 3][jj]);
      ushort4v h4, m4;
      split2x4(v4, h4, m4);
      const size_t base = (size_t)(j0 + jj) * kN + i0 + cq;
      *(ushort4v*)(&Adj2[base]) = h4;
      *(ushort4v*)(&Adj2[PLANE_NN + base]) = m4;
    }
    if (bi != bj) {
      const float4 v4 = make_float4(T1[cq + 0][jj], T1[cq + 1][jj],
                                    T1[cq + 2][jj], T1[cq + 3][jj]);
      ushort4v h4, m4;
      split2x4(v4, h4, m4);
      const size_t base = (size_t)(i0 + jj) * kN + j0 + cq;
      *(ushort4v*)(&Adj2[base]) = h4;
      *(ushort4v*)(&Adj2[PLANE_NN + base]) = m4;
    }
  }
  if (tid < 64) {
    float s = 0.0f;
#pragma unroll 8
    for (int ii = 0; ii < 64; ++ii) s += T0[ii][tid];
    degp[(size_t)bi * kN + j0 + tid] = s;
    if (bi != bj) {
      float s1 = 0.0f;
#pragma unroll 8
      for (int ii = 0; ii < 64; ++ii) s1 += T1[ii][tid];
      degp[(size_t)bj * kN + i0 + tid] = s1;
    }
  }
}

__global__ __launch_bounds__(256) void deg_dis_kernel(
    const float* __restrict__ degp, float* __restrict__ dis) {
  const int j = blockIdx.x * 256 + threadIdx.x;
  float s = 0.0f;
#pragma unroll
  for (int c = 0; c < 64; ++c) s += degp[(size_t)c * kN + j];
  dis[j] = (s > 0.0f) ? (1.0f / sqrtf(s)) : 0.0f;
}

// ============ split-K combines ============
__global__ __launch_bounds__(256) void combine_h(
    const float* __restrict__ hp, const float* __restrict__ dis,
    const float* __restrict__ b0, const float* __restrict__ b1,
    unsigned short* __restrict__ h2) {
  const size_t qd = (size_t)blockIdx.x * 256 + threadIdx.x;
  const int m = (int)(qd >> 8);
  const int c0 = (int)(qd & 255) * 4;
  const size_t off = (size_t)m * 1024 + c0;
  const float4 s0 = *(const float4*)(&hp[off]);
  const float4 s1 = *(const float4*)(&hp[PLANE_H + off]);
  const float4 s2 = *(const float4*)(&hp[2 * PLANE_H + off]);
  const float4 s3 = *(const float4*)(&hp[3 * PLANE_H + off]);
  const float4 bv = (c0 < 512) ? *(const float4*)(&b0[c0])
                               : *(const float4*)(&b1[c0 - 512]);
  const float ds = dis[m];
  float4 v4;
  v4.x = fmaxf(ds * (s0.x + s1.x + s2.x + s3.x) + bv.x, 0.f);
  v4.y = fmaxf(ds * (s0.y + s1.y + s2.y + s3.y) + bv.y, 0.f);
  v4.z = fmaxf(ds * (s0.z + s1.z + s2.z + s3.z) + bv.z, 0.f);
  v4.w = fmaxf(ds * (s0.w + s1.w + s2.w + s3.w) + bv.w, 0.f);
  ushort4v h4, m4;
  split2x4(v4, h4, m4);
  *(ushort4v*)(&h2[off]) = h4;
  *(ushort4v*)(&h2[PLANE_H + off]) = m4;
}

__global__ __launch_bounds__(256) void combine_z(
    const float* __restrict__ zp, const float* __restrict__ dis,
    const float* __restrict__ b0, const float* __restrict__ b1,
    float* __restrict__ out) {
  const size_t qd = (size_t)blockIdx.x * 256 + threadIdx.x;
  const int m = (int)(qd >> 7);
  const int c0 = (int)(qd & 127) * 4;
  const size_t off = (size_t)m * 512 + c0;
  constexpr size_t PZ = (size_t)kN * 512;
  const float4 s0 = *(const float4*)(&zp[off]);
  const float4 s1 = *(const float4*)(&zp[PZ + off]);
  const float4 s2 = *(const float4*)(&zp[2 * PZ + off]);
  const float4 s3 = *(const float4*)(&zp[3 * PZ + off]);
  const float4 bv = (c0 < 256) ? *(const float4*)(&b0[c0])
                               : *(const float4*)(&b1[c0 - 256]);
  const float ds = dis[m];
  float4 v4;
  v4.x = fmaxf(ds * (s0.x + s1.x + s2.x + s3.x) + bv.x, 0.f);
  v4.y = fmaxf(ds * (s0.y + s1.y + s2.y + s3.y) + bv.y, 0.f);
  v4.z = fmaxf(ds * (s0.z + s1.z + s2.z + s3.z) + bv.z, 0.f);
  v4.w = fmaxf(ds * (s0.w + s1.w + s2.w + s3.w) + bv.w, 0.f);
  float* dst = (c0 < 256) ? &out[(size_t)m * 256 + c0]
                          : &out[(size_t)kN * 256 + (size_t)m * 256 + (c0 - 256)];
  *(float4*)dst = v4;
}

// ============ launch ============
extern "C" void kernel_launch(void* const* d_in, const int* in_sizes, int n_in,
                              void* d_out, int out_size, void* d_ws,
                              size_t ws_size, hipStream_t stream) {
  const float* x = (const float*)d_in[0];
  const float* ne = (const float*)d_in[1];
  const float* beta = (const float*)d_in[2];
  const float* delta = (const float*)d_in[3];
  const float* epsm = (const float*)d_in[4];
  const float* Wm = (const float*)d_in[5];
  const float* bm = (const float*)d_in[6];
  const float* Ws = (const float*)d_in[7];
  const float* bs = (const float*)d_in[8];
  const float* mW0 = (const float*)d_in[9];
  const float* mb0 = (const float*)d_in[10];
  const float* mW1 = (const float*)d_in[11];
  const float* mb1 = (const float*)d_in[12];
  const float* sW0 = (const float*)d_in[13];
  const float* sb0 = (const float*)d_in[14];
  const float* sW1 = (const float*)d_in[15];
  const float* sb1 = (const float*)d_in[16];
  float* out = (float*)d_out;

  // WSR (67.1 MB) is dead after adj_transpose; hp/zp (<= 67.1 MB) alias it.
  char* p = (char*)d_ws;
  float* WSR = (float*)p;                     p += PLANE_NN * 4;
  unsigned short* Adj2 = (unsigned short*)p;  p += 2 * PLANE_NN * 2;
  unsigned short* x3 = (unsigned short*)p;    p += 3 * PLANE_XF * 2;  // -> V1t2
  float* XMf = (float*)p;                     p += PLANE_XF * 4;
  float* XSf = (float*)p;                     p += PLANE_XF * 4;
  unsigned short* XM2 = (unsigned short*)p;   p += 2 * PLANE_XF * 2;  // -> h2
  unsigned short* XS2 = (unsigned short*)p;   p += 2 * PLANE_XF * 2;
  unsigned short* M2 = (unsigned short*)p;    p += 2 * PLANE_XF * 2;  // -> V0t2
  unsigned short* CS2 = (unsigned short*)p;   p += 2 * PLANE_XF * 2;
  unsigned short* Wm3 = (unsigned short*)p;   p += 3 * PLANE_W * 2;
  unsigned short* Ws3 = (unsigned short*)p;   p += 3 * PLANE_W * 2;
  unsigned short* mW0t2 = (unsigned short*)p; p += 2 * PLANE_W * 2;
  unsigned short* sW0t2 = (unsigned short*)p; p += 2 * PLANE_W * 2;
  unsigned short* mW1t2 = (unsigned short*)p; p += 2 * PLANE_W1 * 2;
  unsigned short* sW1t2 = (unsigned short*)p; p += 2 * PLANE_W1 * 2;
  float* degp = (float*)p;                    p += (size_t)64 * kN * 4;
  float* sq = (float*)p;                      p += kN * 4;
  float* csum = (float*)p;                    p += kN * 4;
  float* invn = (float*)p;                    p += kN * 4;
  float* dis = (float*)p;                     p += kN * 4;

  float* hp = WSR;   // 4 * PLANE_H floats = PLANE_NN floats exactly
  float* zp = WSR;   // 4 * kN*512 floats = PLANE_NN/2 floats
  unsigned short* V1t2 = x3;
  unsigned short* h2 = XM2;
  unsigned short* V0t2 = M2;

  const dim3 blk(256);
  const int nTri = (kN / 64) * (kN / 64 + 1) / 2;  // 2080

  prep_w<<<dim3(1024, 6), blk, 0, stream>>>(Wm, Ws, mW0, sW0, mW1, sW1, Wm3,
                                            Ws3, mW0t2, sW0t2, mW1t2, sW1t2);
  split_x<<<(kN * kF) / 256, blk, 0, stream>>>(x, x3);

  // 1) x_mean/x_std (split3, full precision) -> f32
  gemm_x<<<dim3(16, 32), blk, 0, stream>>>(x3, Wm3, Ws3, XMf, XSf, bm, bs);

  // 2) row stats + all split2 planes
  row_stats<<<kN, blk, 0, stream>>>(XMf, XSf, M2, CS2, XM2, XS2, sq, csum);

  // 3) ws_raw (triangle + mirror)
  ws_mfma2<<<nTri, blk, 0, stream>>>(M2, CS2, sq, csum, WSR);

  // 4) row inverse norms
  row_invnorm_kernel<<<kN, blk, 0, stream>>>(WSR, invn);

  // 5) adjacency -> Adj2 (transposed 2-plane) + deg partials. WSR dead after.
  adj_transpose<<<nTri, blk, 0, stream>>>(WSR, invn, ne, epsm, beta, delta,
                                          Adj2, degp);
  deg_dis_kernel<<<kN / 256, blk, 0, stream>>>(degp, dis);

  // 6) V0t = (dis_i * XM@W0 | XS@W0)^T  -> split2 CT planes [1024][4096]
  gemm2ct<128, 64><<<dim3(16, 32), blk, 0, stream>>>(
      XM2, XS2, kF, PLANE_XF, mW0t2, sW0t2, kF, PLANE_W, V0t2,
      V0t2 + (size_t)512 * kN, kN, PLANE_V0, 512, kF, dis);

  // 7) h partials: AdjT @ V0t, split-K=4, XCD-swizzled (8*8*4*4 = 1024 blocks)
  gemm2k<128, 128, 8, 4, 4><<<1024, blk, 0, stream>>>(
      Adj2, kN, PLANE_NN, V0t2, kN, PLANE_V0, hp, 1024, kN, kN / 4);
  combine_h<<<(int)(PLANE_H / 4 / 256), blk, 0, stream>>>(hp, dis, mb0, sb0, h2);

  // 8) V1t = (dis_i * h@W1)^T -> split2 CT planes [512][4096]
  gemm2ct<64, 64><<<dim3(8, 64), blk, 0, stream>>>(
      h2, h2 + 512, 1024, PLANE_H, mW1t2, sW1t2, kF, PLANE_W1, V1t2,
      V1t2 + (size_t)256 * kN, kN, PLANE_V1, 256, kF, dis);

  // 9) z partials: AdjT @ V1t, split-K=4, XCD-swizzled (8*4*4*4 = 512 blocks)
  gemm2k<128, 128, 4, 4, 4><<<512, blk, 0, stream>>>(
      Adj2, kN, PLANE_NN, V1t2, kN, PLANE_V1, zp, 512, kN, kN / 4);
  combine_z<<<(int)((size_t)kN * 512 / 4 / 256), blk, 0, stream>>>(zp, dis, mb1,
                                                                   sb1, out);
}